// Round 1
// baseline (2380.083 us; speedup 1.0000x reference)
//
#include <hip/hip_runtime.h>
#include <math.h>

#define S 2048
#define DIM 1024
#define H 16
#define G 4
#define HPG 4
#define DK 64
#define DV 64
#define NCMP 127
#define JBLK 32
#define NSEL 16
#define WWIN 512
#define GH 32

// ---------------- RoPE cos/sin table (fp64-accurate, matches np reference) ---
__global__ void rope_table(float* __restrict__ cosT, float* __restrict__ sinT) {
  int idx = blockIdx.x * blockDim.x + threadIdx.x;
  if (idx >= S * 32) return;
  int s = idx >> 5, i = idx & 31;
  double inv = pow(10000.0, -2.0 * (double)i / 64.0);
  double ang = (double)s * inv;
  cosT[idx] = (float)cos(ang);
  sinT[idx] = (float)sin(ang);
}

// ---------------- generic fp32 tiled GEMM: C[M,N] = A[M,K] @ B[K,N] ----------
// M,N multiples of 64; K multiple of 16.
__global__ __launch_bounds__(256) void gemm_f32(const float* __restrict__ A,
                                                const float* __restrict__ B,
                                                float* __restrict__ C,
                                                int M, int N, int K) {
  __shared__ float As[16][64];
  __shared__ float Bs[16][64];
  int tid = threadIdx.x;
  int bm = blockIdx.y, bn = blockIdx.x;
  int tr = tid >> 4, tc = tid & 15;
  float acc[4][4] = {{0.f}};
  int arow = tid >> 2;
  int acol = (tid & 3) << 2;
  int brow = tid >> 4;
  int bcol = (tid & 15) << 2;
  const float* Ab = A + (size_t)(bm * 64) * K;
  const float* Bb = B + bn * 64;
  for (int k0 = 0; k0 < K; k0 += 16) {
    float4 av = *(const float4*)(Ab + (size_t)arow * K + k0 + acol);
    float4 bv = *(const float4*)(Bb + (size_t)(k0 + brow) * N + bcol);
    As[acol + 0][arow] = av.x;
    As[acol + 1][arow] = av.y;
    As[acol + 2][arow] = av.z;
    As[acol + 3][arow] = av.w;
    *(float4*)(&Bs[brow][bcol]) = bv;
    __syncthreads();
#pragma unroll
    for (int kk = 0; kk < 16; ++kk) {
      float a[4], b[4];
#pragma unroll
      for (int q = 0; q < 4; ++q) {
        a[q] = As[kk][(tr << 2) + q];
        b[q] = Bs[kk][(tc << 2) + q];
      }
#pragma unroll
      for (int i = 0; i < 4; ++i)
#pragma unroll
        for (int jj = 0; jj < 4; ++jj) acc[i][jj] += a[i] * b[jj];
    }
    __syncthreads();
  }
  for (int i = 0; i < 4; ++i)
    for (int jj = 0; jj < 4; ++jj)
      C[(size_t)(bm * 64 + (tr << 2) + i) * N + bn * 64 + (tc << 2) + jj] = acc[i][jj];
}

// ---------------- in-place RoPE on [S][NH][64] --------------------------------
__global__ void rope_apply(float* __restrict__ a, const float* __restrict__ cosT,
                           const float* __restrict__ sinT, int NH, int total) {
  int idx = blockIdx.x * blockDim.x + threadIdx.x;
  if (idx >= total) return;
  int i = idx & 31;
  int rest = idx >> 5;
  int n = rest % NH;
  int s = rest / NH;
  float c = cosT[s * 32 + i], sn = sinT[s * 32 + i];
  float* base = a + (size_t)(s * NH + n) * 64;
  float x1 = base[i], x2 = base[i + 32];
  base[i] = x1 * c - x2 * sn;
  base[i + 32] = x2 * c + x1 * sn;
}

// ---------------- avg-pool compressed K/V: [S][G][64] -> [G][NCMP][64] --------
__global__ void pool_cmp(const float* __restrict__ Kcr, const float* __restrict__ Vcr,
                         float* __restrict__ Kc, float* __restrict__ Vc) {
  int c = blockIdx.x, g = blockIdx.y, d = threadIdx.x;
  float sk = 0.f, sv = 0.f;
  for (int l = 0; l < 32; ++l) {
    int t = c * 16 + l;
    sk += Kcr[(size_t)(t * G + g) * 64 + d];
    sv += Vcr[(size_t)(t * G + g) * 64 + d];
  }
  Kc[(size_t)(g * NCMP + c) * 64 + d] = sk * (1.f / 32.f);
  Vc[(size_t)(g * NCMP + c) * 64 + d] = sv * (1.f / 32.f);
}

// ---------------- compressed attention + selection scoring + top-k ------------
// block = (s, g); 256 threads = 4 waves (one per head)
__global__ __launch_bounds__(256) void cmp_attn(const float* __restrict__ Q,
                                                const float* __restrict__ Kc,
                                                const float* __restrict__ Vc,
                                                float* __restrict__ Ocmp,
                                                unsigned int* __restrict__ selm) {
  int s = blockIdx.x, g = blockIdx.y;
  __shared__ float q[4][64];
  __shared__ float kc[NCMP][65];
  __shared__ float sc[4][NCMP];
  __shared__ float pgp[4][JBLK];
  __shared__ float pg[JBLK];
  int tid = threadIdx.x;
  {
    int h = tid >> 6, d = tid & 63;
    q[h][d] = Q[(size_t)(s * H + g * HPG + h) * 64 + d];
  }
  const float* kcg = Kc + (size_t)g * NCMP * 64;
  for (int e = tid; e < NCMP * 64; e += 256) kc[e >> 6][e & 63] = kcg[e];
  __syncthreads();

  int lane = tid & 63, w = tid >> 6;  // w = head
  bool any_vis = (s >= 31);
  float v0 = -INFINITY, v1 = -INFINITY;
#pragma unroll
  for (int r = 0; r < 2; ++r) {
    int c = lane + r * 64;
    if (c < NCMP && (c * 16 + 32 <= s + 1)) {
      float acc = 0.f;
#pragma unroll
      for (int kk = 0; kk < 64; ++kk) acc += q[w][kk] * kc[c][kk];
      float val = acc * 0.125f;
      if (r) v1 = val; else v0 = val;
    }
  }
  float p0 = 0.f, p1 = 0.f;
  if (any_vis) {
    float m = fmaxf(v0, v1);
    for (int off = 32; off; off >>= 1) m = fmaxf(m, __shfl_xor(m, off));
    p0 = (v0 > -INFINITY) ? expf(v0 - m) : 0.f;
    p1 = (v1 > -INFINITY) ? expf(v1 - m) : 0.f;
    float sum = p0 + p1;
    for (int off = 32; off; off >>= 1) sum += __shfl_xor(sum, off);
    p0 /= sum;
    p1 /= sum;
  }
  sc[w][lane] = p0;
  if (lane + 64 < NCMP) sc[w][lane + 64] = p1;
  __syncthreads();

  // O_cmp = p @ V_cmp
  {
    int h = tid >> 6, d = tid & 63;
    float o = 0.f;
    for (int c = 0; c < NCMP; ++c) o += sc[h][c] * Vc[(size_t)(g * NCMP + c) * 64 + d];
    Ocmp[(size_t)(s * H + g * HPG + h) * 64 + d] = o;
  }

  // p_grp: sum over heads, overlap-weighted over c
  if (tid < 128) {
    int h = tid >> 5, j = tid & 31;
    float a = 0.f;
    for (int c = 0; c < NCMP; ++c) {
      int lo = max(c * 16, j * 64);
      int hi = min(c * 16 + 32, j * 64 + 64);
      if (hi > lo) a += sc[h][c] * (float)(hi - lo) * (1.f / 32.f);
    }
    pgp[h][j] = a;
  }
  __syncthreads();
  if (tid < JBLK) pg[tid] = pgp[0][tid] + pgp[1][tid] + pgp[2][tid] + pgp[3][tid];
  __syncthreads();

  if (tid == 0) {
    float scj[JBLK];
    int cur = s >> 6;
    for (int j = 0; j < JBLK; ++j) {
      float v = (j * 64 <= s) ? pg[j] : -1e30f;
      if (j == 0 || j == cur) v = 1e9f;
      scj[j] = v;
    }
    unsigned int mask = 0;
    for (int n = 0; n < NSEL; ++n) {
      int bi = 0;
      float bv = -INFINITY;
      for (int j = 0; j < JBLK; ++j)
        if (scj[j] > bv) { bv = scj[j]; bi = j; }
      mask |= 1u << bi;
      scj[bi] = -INFINITY;
    }
    selm[s * G + g] = mask;
  }
}

// ---------------- selection attention ----------------------------------------
__global__ __launch_bounds__(256) void sel_attn(const float* __restrict__ Q,
                                                const float* __restrict__ K,
                                                const float* __restrict__ V,
                                                const unsigned int* __restrict__ selm,
                                                float* __restrict__ Osel) {
  int s = blockIdx.x, g = blockIdx.y;
  __shared__ int blks[NSEL];
  __shared__ float q[64];
  __shared__ float p[1024];
  __shared__ float part[4][64];
  __shared__ float red[8];
  int tid = threadIdx.x;
  if (tid == 0) {
    unsigned int m = selm[s * G + g];
    int n = 0;
    for (int j = 0; j < JBLK && n < NSEL; ++j)
      if ((m >> j) & 1u) blks[n++] = j;
  }
  __syncthreads();
  for (int h = 0; h < 4; ++h) {
    if (tid < 64) q[tid] = Q[(size_t)(s * H + g * HPG + h) * 64 + tid];
    __syncthreads();
    float vals[4];
    float lm = -INFINITY;
#pragma unroll
    for (int r = 0; r < 4; ++r) {
      int i = tid + r * 256;
      int u = blks[i >> 6] * 64 + (i & 63);
      float v = -INFINITY;
      if (u <= s) {
        const float4* kp = (const float4*)&K[(size_t)(u * G + g) * 64];
        const float4* qp = (const float4*)q;
        float acc = 0.f;
#pragma unroll
        for (int kk = 0; kk < 16; ++kk) {
          float4 a = qp[kk], b = kp[kk];
          acc += a.x * b.x + a.y * b.y + a.z * b.z + a.w * b.w;
        }
        v = acc * 0.125f;
      }
      vals[r] = v;
      lm = fmaxf(lm, v);
    }
    for (int off = 32; off; off >>= 1) lm = fmaxf(lm, __shfl_xor(lm, off));
    if ((tid & 63) == 0) red[tid >> 6] = lm;
    __syncthreads();
    float m = fmaxf(fmaxf(red[0], red[1]), fmaxf(red[2], red[3]));
    float pv[4];
    float ls = 0.f;
#pragma unroll
    for (int r = 0; r < 4; ++r) {
      float e = (vals[r] > -INFINITY) ? expf(vals[r] - m) : 0.f;
      pv[r] = e;
      ls += e;
    }
    for (int off = 32; off; off >>= 1) ls += __shfl_xor(ls, off);
    if ((tid & 63) == 0) red[4 + (tid >> 6)] = ls;
    __syncthreads();
    float inv = 1.f / (red[4] + red[5] + red[6] + red[7]);
#pragma unroll
    for (int r = 0; r < 4; ++r) p[tid + r * 256] = pv[r] * inv;
    __syncthreads();
    int ck = tid >> 6, d = tid & 63;
    float o = 0.f;
    for (int r = 0; r < 256; ++r) {
      int i = ck * 256 + r;
      int u = blks[i >> 6] * 64 + (i & 63);
      o += p[i] * V[(size_t)(u * G + g) * 64 + d];
    }
    part[ck][d] = o;
    __syncthreads();
    if (tid < 64)
      Osel[(size_t)(s * H + g * HPG + h) * 64 + tid] =
          part[0][tid] + part[1][tid] + part[2][tid] + part[3][tid];
    __syncthreads();
  }
}

// ---------------- sliding-window attention ------------------------------------
__global__ __launch_bounds__(256) void win_attn(const float* __restrict__ Q,
                                                const float* __restrict__ K,
                                                const float* __restrict__ V,
                                                float* __restrict__ Owin) {
  int s = blockIdx.x, g = blockIdx.y;
  __shared__ float q[64];
  __shared__ float p[WWIN];
  __shared__ float part[4][64];
  __shared__ float red[8];
  int tid = threadIdx.x;
  int base = s - (WWIN - 1);
  for (int h = 0; h < 4; ++h) {
    if (tid < 64) q[tid] = Q[(size_t)(s * H + g * HPG + h) * 64 + tid];
    __syncthreads();
    float vals[2];
    float lm = -INFINITY;
#pragma unroll
    for (int r = 0; r < 2; ++r) {
      int i = tid + r * 256;
      int u = base + i;
      float v = -INFINITY;
      if (u >= 0) {
        const float4* kp = (const float4*)&K[(size_t)(u * G + g) * 64];
        const float4* qp = (const float4*)q;
        float acc = 0.f;
#pragma unroll
        for (int kk = 0; kk < 16; ++kk) {
          float4 a = qp[kk], b = kp[kk];
          acc += a.x * b.x + a.y * b.y + a.z * b.z + a.w * b.w;
        }
        v = acc * 0.125f;
      }
      vals[r] = v;
      lm = fmaxf(lm, v);
    }
    for (int off = 32; off; off >>= 1) lm = fmaxf(lm, __shfl_xor(lm, off));
    if ((tid & 63) == 0) red[tid >> 6] = lm;
    __syncthreads();
    float m = fmaxf(fmaxf(red[0], red[1]), fmaxf(red[2], red[3]));
    float pv[2];
    float ls = 0.f;
#pragma unroll
    for (int r = 0; r < 2; ++r) {
      float e = (vals[r] > -INFINITY) ? expf(vals[r] - m) : 0.f;
      pv[r] = e;
      ls += e;
    }
    for (int off = 32; off; off >>= 1) ls += __shfl_xor(ls, off);
    if ((tid & 63) == 0) red[4 + (tid >> 6)] = ls;
    __syncthreads();
    float inv = 1.f / (red[4] + red[5] + red[6] + red[7]);
#pragma unroll
    for (int r = 0; r < 2; ++r) p[tid + r * 256] = pv[r] * inv;
    __syncthreads();
    int ck = tid >> 6, d = tid & 63;
    float o = 0.f;
    for (int r = 0; r < 128; ++r) {
      int i = ck * 128 + r;
      int u = base + i;
      if (u >= 0) o += p[i] * V[(size_t)(u * G + g) * 64 + d];
    }
    part[ck][d] = o;
    __syncthreads();
    if (tid < 64)
      Owin[(size_t)(s * H + g * HPG + h) * 64 + tid] =
          part[0][tid] + part[1][tid] + part[2][tid] + part[3][tid];
    __syncthreads();
  }
}

// ---------------- gating MLP ---------------------------------------------------
__global__ void gate_kernel(const float* __restrict__ Q, const float* __restrict__ w1,
                            const float* __restrict__ b1, const float* __restrict__ w2,
                            const float* __restrict__ b2, float* __restrict__ gates) {
  int idx = blockIdx.x * blockDim.x + threadIdx.x;
  if (idx >= S * G) return;
  int s = idx >> 2, g = idx & 3;
  float qm[64];
#pragma unroll
  for (int d = 0; d < 64; ++d) {
    float a = 0.f;
    for (int hp = 0; hp < HPG; ++hp) a += Q[(size_t)(s * H + g * HPG + hp) * 64 + d];
    qm[d] = a * 0.25f;
  }
  float gl[3] = {b2[0], b2[1], b2[2]};
  for (int j = 0; j < GH; ++j) {
    float z = b1[j];
    for (int d = 0; d < 64; ++d) z += qm[d] * w1[d * GH + j];
    float sl = z / (1.f + expf(-z));
    gl[0] += sl * w2[j * 3 + 0];
    gl[1] += sl * w2[j * 3 + 1];
    gl[2] += sl * w2[j * 3 + 2];
  }
  float m = fmaxf(gl[0], fmaxf(gl[1], gl[2]));
  float e0 = expf(gl[0] - m), e1 = expf(gl[1] - m), e2 = expf(gl[2] - m);
  float inv = 1.f / (e0 + e1 + e2);
  float p0 = e0 * inv, p1 = e1 * inv, p2 = e2 * inv;
  int am = (gl[0] >= gl[1] && gl[0] >= gl[2]) ? 0 : ((gl[1] >= gl[2]) ? 1 : 2);
  float t1 = (am == 0) ? fmaxf(gl[1], gl[2]) : ((am == 1) ? fmaxf(gl[0], gl[2]) : fmaxf(gl[0], gl[1]));
  if (m - t1 > 50.f) {
    p0 = (am == 0) ? 1.f : 0.f;
    p1 = (am == 1) ? 1.f : 0.f;
    p2 = (am == 2) ? 1.f : 0.f;
  }
  gates[idx * 3 + 0] = p0;
  gates[idx * 3 + 1] = p1;
  gates[idx * 3 + 2] = p2;
}

// ---------------- combine branches ---------------------------------------------
__global__ void combine(const float* __restrict__ Oc, const float* __restrict__ Os,
                        const float* __restrict__ Ow, const float* __restrict__ gates,
                        float* __restrict__ O) {
  int idx = blockIdx.x * blockDim.x + threadIdx.x;
  if (idx >= S * H * DV) return;
  int h = (idx >> 6) & 15;
  int s = idx >> 10;
  int g = h >> 2;
  const float* gp = &gates[(size_t)(s * G + g) * 3];
  O[idx] = gp[0] * Oc[idx] + gp[1] * Os[idx] + gp[2] * Ow[idx];
}

// ---------------- host launch ---------------------------------------------------
extern "C" void kernel_launch(void* const* d_in, const int* in_sizes, int n_in,
                              void* d_out, int out_size, void* d_ws, size_t ws_size,
                              hipStream_t stream) {
  const float* x = (const float*)d_in[0];
  const float* W_Q = (const float*)d_in[1];
  const float* W_K_sel = (const float*)d_in[2];
  const float* W_V_sel = (const float*)d_in[3];
  const float* W_K_win = (const float*)d_in[4];
  const float* W_V_win = (const float*)d_in[5];
  const float* W_K_cmp = (const float*)d_in[6];
  const float* W_V_cmp = (const float*)d_in[7];
  const float* W_out = (const float*)d_in[8];
  const float* gw1 = (const float*)d_in[9];
  const float* gb1 = (const float*)d_in[10];
  const float* gw2 = (const float*)d_in[11];
  const float* gb2 = (const float*)d_in[12];

  float* w = (float*)d_ws;
  float* cosT = w;  w += S * 32;
  float* sinT = w;  w += S * 32;
  float* Qb   = w;  w += S * H * DK;
  float* Ksel = w;  w += S * G * DK;
  float* Vsel = w;  w += S * G * DV;
  float* Kwin = w;  w += S * G * DK;
  float* Vwin = w;  w += S * G * DV;
  float* Kcr  = w;  w += S * G * DK;
  float* Vcr  = w;  w += S * G * DV;
  float* Kc   = w;  w += G * NCMP * DK;
  float* Vc   = w;  w += G * NCMP * DV;
  float* Ocmp = w;  w += S * H * DV;
  float* Osel = w;  w += S * H * DV;
  float* Owin = w;  w += S * H * DV;
  float* gates= w;  w += S * G * 3;
  float* Ocomb= w;  w += S * H * DV;
  unsigned int* selm = (unsigned int*)w;

  rope_table<<<(S * 32 + 255) / 256, 256, 0, stream>>>(cosT, sinT);

  gemm_f32<<<dim3(DIM / 64, S / 64), 256, 0, stream>>>(x, W_Q, Qb, S, H * DK, DIM);
  gemm_f32<<<dim3((G * DK) / 64, S / 64), 256, 0, stream>>>(x, W_K_sel, Ksel, S, G * DK, DIM);
  gemm_f32<<<dim3((G * DV) / 64, S / 64), 256, 0, stream>>>(x, W_V_sel, Vsel, S, G * DV, DIM);
  gemm_f32<<<dim3((G * DK) / 64, S / 64), 256, 0, stream>>>(x, W_K_win, Kwin, S, G * DK, DIM);
  gemm_f32<<<dim3((G * DV) / 64, S / 64), 256, 0, stream>>>(x, W_V_win, Vwin, S, G * DV, DIM);
  gemm_f32<<<dim3((G * DK) / 64, S / 64), 256, 0, stream>>>(x, W_K_cmp, Kcr, S, G * DK, DIM);
  gemm_f32<<<dim3((G * DV) / 64, S / 64), 256, 0, stream>>>(x, W_V_cmp, Vcr, S, G * DV, DIM);

  rope_apply<<<(S * H * 32 + 255) / 256, 256, 0, stream>>>(Qb, cosT, sinT, H, S * H * 32);
  rope_apply<<<(S * G * 32 + 255) / 256, 256, 0, stream>>>(Ksel, cosT, sinT, G, S * G * 32);
  rope_apply<<<(S * G * 32 + 255) / 256, 256, 0, stream>>>(Kwin, cosT, sinT, G, S * G * 32);
  rope_apply<<<(S * G * 32 + 255) / 256, 256, 0, stream>>>(Kcr, cosT, sinT, G, S * G * 32);

  pool_cmp<<<dim3(NCMP, G), 64, 0, stream>>>(Kcr, Vcr, Kc, Vc);

  cmp_attn<<<dim3(S, G), 256, 0, stream>>>(Qb, Kc, Vc, Ocmp, selm);
  sel_attn<<<dim3(S, G), 256, 0, stream>>>(Qb, Ksel, Vsel, selm, Osel);
  win_attn<<<dim3(S, G), 256, 0, stream>>>(Qb, Kwin, Vwin, Owin);

  gate_kernel<<<(S * G + 255) / 256, 256, 0, stream>>>(Qb, gw1, gb1, gw2, gb2, gates);
  combine<<<(S * H * DV + 255) / 256, 256, 0, stream>>>(Ocmp, Osel, Owin, gates, Ocomb);

  gemm_f32<<<dim3(DIM / 64, S / 64), 256, 0, stream>>>(Ocomb, W_out, (float*)d_out, S, DIM, H * DV);
}

// Round 2
// 1984.324 us; speedup vs baseline: 1.1994x; 1.1994x over previous
//
#include <hip/hip_runtime.h>
#include <math.h>

#define S 2048
#define DIM 1024
#define H 16
#define G 4
#define HPG 4
#define DK 64
#define DV 64
#define NCMP 127
#define JBLK 32
#define NSEL 16
#define WWIN 512
#define GH 32

// ---------------- RoPE cos/sin table (fp64-accurate, matches np reference) ---
__global__ void rope_table(float* __restrict__ cosT, float* __restrict__ sinT) {
  int idx = blockIdx.x * blockDim.x + threadIdx.x;
  if (idx >= S * 32) return;
  int s = idx >> 5, i = idx & 31;
  double inv = pow(10000.0, -2.0 * (double)i / 64.0);
  double ang = (double)s * inv;
  cosT[idx] = (float)cos(ang);
  sinT[idx] = (float)sin(ang);
}

// ---------------- fp32 tiled GEMM body (64x64 tile, 4x4/thread) --------------
__device__ __forceinline__ void gemm_body(const float* __restrict__ A,
                                          const float* __restrict__ B,
                                          float* __restrict__ C,
                                          int N, int K, int bm, int bn,
                                          float (*As)[64], float (*Bs)[64]) {
  int tid = threadIdx.x;
  int tr = tid >> 4, tc = tid & 15;
  float acc[4][4] = {{0.f}};
  int arow = tid >> 2;
  int acol = (tid & 3) << 2;
  int brow = tid >> 4;
  int bcol = (tid & 15) << 2;
  const float* Ab = A + (size_t)(bm * 64) * K;
  const float* Bb = B + bn * 64;
  for (int k0 = 0; k0 < K; k0 += 16) {
    float4 av = *(const float4*)(Ab + (size_t)arow * K + k0 + acol);
    float4 bv = *(const float4*)(Bb + (size_t)(k0 + brow) * N + bcol);
    As[acol + 0][arow] = av.x;
    As[acol + 1][arow] = av.y;
    As[acol + 2][arow] = av.z;
    As[acol + 3][arow] = av.w;
    *(float4*)(&Bs[brow][bcol]) = bv;
    __syncthreads();
#pragma unroll
    for (int kk = 0; kk < 16; ++kk) {
      float a[4], b[4];
#pragma unroll
      for (int q = 0; q < 4; ++q) {
        a[q] = As[kk][(tr << 2) + q];
        b[q] = Bs[kk][(tc << 2) + q];
      }
#pragma unroll
      for (int i = 0; i < 4; ++i)
#pragma unroll
        for (int jj = 0; jj < 4; ++jj) acc[i][jj] += a[i] * b[jj];
    }
    __syncthreads();
  }
  for (int i = 0; i < 4; ++i)
    for (int jj = 0; jj < 4; ++jj)
      C[(size_t)(bm * 64 + (tr << 2) + i) * N + bn * 64 + (tc << 2) + jj] = acc[i][jj];
}

__global__ __launch_bounds__(256) void gemm_f32(const float* __restrict__ A,
                                                const float* __restrict__ B,
                                                float* __restrict__ C,
                                                int N, int K) {
  __shared__ float As[16][64];
  __shared__ float Bs[16][64];
  gemm_body(A, B, C, N, K, blockIdx.y, blockIdx.x, As, Bs);
}

// batched K/V projections: 6 weight matrices, outputs contiguous (z*S*256)
__global__ __launch_bounds__(256) void gemm_kv(const float* __restrict__ x,
                                               const float* __restrict__ W0,
                                               const float* __restrict__ W1,
                                               const float* __restrict__ W2,
                                               const float* __restrict__ W3,
                                               const float* __restrict__ W4,
                                               const float* __restrict__ W5,
                                               float* __restrict__ out) {
  __shared__ float As[16][64];
  __shared__ float Bs[16][64];
  int z = blockIdx.z;
  const float* B;
  switch (z) {
    case 0: B = W0; break;
    case 1: B = W1; break;
    case 2: B = W2; break;
    case 3: B = W3; break;
    case 4: B = W4; break;
    default: B = W5; break;
  }
  gemm_body(x, B, out + (size_t)z * S * 256, 256, DIM, blockIdx.y, blockIdx.x, As, Bs);
}

// ---------------- in-place RoPE on [S][NH][64] --------------------------------
__global__ void rope_apply(float* __restrict__ a, const float* __restrict__ cosT,
                           const float* __restrict__ sinT, int NH, int total) {
  int idx = blockIdx.x * blockDim.x + threadIdx.x;
  if (idx >= total) return;
  int i = idx & 31;
  int rest = idx >> 5;
  int n = rest % NH;
  int s = rest / NH;
  float c = cosT[s * 32 + i], sn = sinT[s * 32 + i];
  float* base = a + (size_t)(s * NH + n) * 64;
  float x1 = base[i], x2 = base[i + 32];
  base[i] = x1 * c - x2 * sn;
  base[i + 32] = x2 * c + x1 * sn;
}

// ---------------- avg-pool compressed K/V -------------------------------------
__global__ void pool_cmp(const float* __restrict__ Kcr, const float* __restrict__ Vcr,
                         float* __restrict__ Kc, float* __restrict__ Vc) {
  int c = blockIdx.x, g = blockIdx.y, d = threadIdx.x;
  float sk = 0.f, sv = 0.f;
  for (int l = 0; l < 32; ++l) {
    int t = c * 16 + l;
    sk += Kcr[(size_t)(t * G + g) * 64 + d];
    sv += Vcr[(size_t)(t * G + g) * 64 + d];
  }
  Kc[(size_t)(g * NCMP + c) * 64 + d] = sk * (1.f / 32.f);
  Vc[(size_t)(g * NCMP + c) * 64 + d] = sv * (1.f / 32.f);
}

// ---------------- compressed attention + selection top-k ----------------------
__global__ __launch_bounds__(256) void cmp_attn(const float* __restrict__ Q,
                                                const float* __restrict__ Kc,
                                                const float* __restrict__ Vc,
                                                float* __restrict__ Ocmp,
                                                unsigned int* __restrict__ selm) {
  int s = blockIdx.x, g = blockIdx.y;
  __shared__ float q4[4][64];
  __shared__ float sc[4][128];
  __shared__ float pgp[4][JBLK];
  __shared__ float pg[JBLK];
  int tid = threadIdx.x;
  {
    int h = tid >> 6, d = tid & 63;
    q4[h][d] = Q[(size_t)(s * H + g * HPG + h) * 64 + d];
  }
  __syncthreads();

  // scores: one key per thread (tid < 127), all 4 heads
  if (tid < NCMP) {
    int c = tid;
    bool vis = (c * 16 + 32 <= s + 1);
    float acc[4] = {0.f, 0.f, 0.f, 0.f};
    const float* kr = &Kc[(size_t)(g * NCMP + c) * 64];
#pragma unroll
    for (int kk = 0; kk < 64; kk += 4) {
      float4 kv = *(const float4*)&kr[kk];
#pragma unroll
      for (int h = 0; h < 4; ++h) {
        float4 qv = *(const float4*)&q4[h][kk];
        acc[h] += qv.x * kv.x + qv.y * kv.y + qv.z * kv.z + qv.w * kv.w;
      }
    }
#pragma unroll
    for (int h = 0; h < 4; ++h) sc[h][c] = vis ? acc[h] * 0.125f : -INFINITY;
  }
  __syncthreads();

  // softmax per head (wave w = head)
  int w = tid >> 6, lane = tid & 63;
  {
    float v0 = sc[w][lane];
    float v1 = (lane + 64 < NCMP) ? sc[w][lane + 64] : -INFINITY;
    float m = fmaxf(v0, v1);
    for (int off = 32; off; off >>= 1) m = fmaxf(m, __shfl_xor(m, off));
    float e0 = (m > -INFINITY && v0 > -INFINITY) ? expf(v0 - m) : 0.f;
    float e1 = (m > -INFINITY && v1 > -INFINITY) ? expf(v1 - m) : 0.f;
    float sum = e0 + e1;
    for (int off = 32; off; off >>= 1) sum += __shfl_xor(sum, off);
    float inv = (sum > 0.f) ? 1.f / sum : 0.f;
    sc[w][lane] = e0 * inv;
    if (lane + 64 < NCMP) sc[w][lane + 64] = e1 * inv;
  }
  __syncthreads();

  // O_cmp = p @ V_cmp  (V row reused by all 4 heads? here h fixed per wave)
  {
    int h = tid >> 6, d = tid & 63;
    float o = 0.f;
    for (int c = 0; c < NCMP; ++c) o += sc[h][c] * Vc[(size_t)(g * NCMP + c) * 64 + d];
    Ocmp[(size_t)(s * H + g * HPG + h) * 64 + d] = o;
  }

  // p_grp: overlap-weighted map to selection blocks, summed over heads
  if (tid < 128) {
    int h = tid >> 5, j = tid & 31;
    float a = 0.f;
    for (int c = 0; c < NCMP; ++c) {
      int lo = max(c * 16, j * 64);
      int hi = min(c * 16 + 32, j * 64 + 64);
      if (hi > lo) a += sc[h][c] * (float)(hi - lo) * (1.f / 32.f);
    }
    pgp[h][j] = a;
  }
  __syncthreads();
  if (tid < JBLK) pg[tid] = pgp[0][tid] + pgp[1][tid] + pgp[2][tid] + pgp[3][tid];
  __syncthreads();

  if (tid == 0) {
    float scj[JBLK];
    int cur = s >> 6;
    for (int j = 0; j < JBLK; ++j) {
      float v = (j * 64 <= s) ? pg[j] : -1e30f;
      if (j == 0 || j == cur) v = 1e9f;
      scj[j] = v;
    }
    unsigned int mask = 0;
    for (int n = 0; n < NSEL; ++n) {
      int bi = 0;
      float bv = -INFINITY;
      for (int j = 0; j < JBLK; ++j)
        if (scj[j] > bv) { bv = scj[j]; bi = j; }
      mask |= 1u << bi;
      scj[bi] = -INFINITY;
    }
    selm[s * G + g] = mask;
  }
}

// ---------------- selection attention (all 4 heads in one pass) ---------------
__global__ __launch_bounds__(256) void sel_attn(const float* __restrict__ Q,
                                                const float* __restrict__ K,
                                                const float* __restrict__ V,
                                                const unsigned int* __restrict__ selm,
                                                float* __restrict__ Osel) {
  int s = blockIdx.x, g = blockIdx.y;
  __shared__ float q4[4][64];
  __shared__ float p[4][1024];
  __shared__ float part[4][4][64];
  __shared__ int blks[NSEL];
  int tid = threadIdx.x;
  if (tid == 0) {
    unsigned int m = selm[s * G + g];
    int n = 0;
    for (int j = 0; j < JBLK && n < NSEL; ++j)
      if ((m >> j) & 1u) blks[n++] = j;
  }
  {
    int h = tid >> 6, d = tid & 63;
    q4[h][d] = Q[(size_t)(s * H + g * HPG + h) * 64 + d];
  }
  __syncthreads();

  // ---- scores: 4 keys/thread, 4 heads each (K row loaded once for 4 heads)
  float acc[4][4];
#pragma unroll
  for (int r = 0; r < 4; ++r)
#pragma unroll
    for (int h = 0; h < 4; ++h) acc[r][h] = 0.f;
  int u_[4];
  bool ok[4];
#pragma unroll
  for (int r = 0; r < 4; ++r) {
    int i = r * 256 + tid;
    int u = blks[i >> 6] * 64 + (i & 63);
    u_[r] = u;
    ok[r] = (u <= s);
  }
#pragma unroll
  for (int kk = 0; kk < 64; kk += 4) {
    float4 qv[4];
#pragma unroll
    for (int h = 0; h < 4; ++h) qv[h] = *(const float4*)&q4[h][kk];
#pragma unroll
    for (int r = 0; r < 4; ++r) {
      float4 kv = *(const float4*)&K[(size_t)(u_[r] * G + g) * 64 + kk];
#pragma unroll
      for (int h = 0; h < 4; ++h)
        acc[r][h] += qv[h].x * kv.x + qv[h].y * kv.y + qv[h].z * kv.z + qv[h].w * kv.w;
    }
  }
#pragma unroll
  for (int r = 0; r < 4; ++r) {
    int i = r * 256 + tid;
#pragma unroll
    for (int h = 0; h < 4; ++h) p[h][i] = ok[r] ? acc[r][h] * 0.125f : -INFINITY;
  }
  __syncthreads();

  // ---- softmax: wave w handles head w
  int w = tid >> 6, lane = tid & 63;
  {
    float vals[16];
    float m = -INFINITY;
#pragma unroll
    for (int r = 0; r < 16; ++r) {
      vals[r] = p[w][lane + 64 * r];
      m = fmaxf(m, vals[r]);
    }
    for (int off = 32; off; off >>= 1) m = fmaxf(m, __shfl_xor(m, off));
    float sum = 0.f;
#pragma unroll
    for (int r = 0; r < 16; ++r) {
      float e = (vals[r] > -INFINITY) ? expf(vals[r] - m) : 0.f;
      vals[r] = e;
      sum += e;
    }
    for (int off = 32; off; off >>= 1) sum += __shfl_xor(sum, off);
    float inv = 1.f / sum;  // current token always visible -> sum > 0
#pragma unroll
    for (int r = 0; r < 16; ++r) p[w][lane + 64 * r] = vals[r] * inv;
  }
  __syncthreads();

  // ---- PV: V row element loaded once, reused for 4 heads
  int ck = tid >> 6, d = tid & 63;
  float o[4] = {0.f, 0.f, 0.f, 0.f};
  for (int i0 = ck * 256; i0 < ck * 256 + 256; i0 += 4) {
    float4 p0 = *(const float4*)&p[0][i0];
    float4 p1 = *(const float4*)&p[1][i0];
    float4 p2 = *(const float4*)&p[2][i0];
    float4 p3 = *(const float4*)&p[3][i0];
#define SEL_STEP(T, C)                                                      \
    {                                                                       \
      int i = i0 + T;                                                       \
      int u = blks[i >> 6] * 64 + (i & 63);                                 \
      float v = V[(size_t)(u * G + g) * 64 + d];                            \
      o[0] += p0.C * v; o[1] += p1.C * v; o[2] += p2.C * v; o[3] += p3.C * v; \
    }
    SEL_STEP(0, x) SEL_STEP(1, y) SEL_STEP(2, z) SEL_STEP(3, w)
#undef SEL_STEP
  }
#pragma unroll
  for (int h = 0; h < 4; ++h) part[ck][h][d] = o[h];
  __syncthreads();
  {
    int h = tid >> 6;
    Osel[(size_t)(s * H + g * HPG + h) * 64 + d] =
        part[0][h][d] + part[1][h][d] + part[2][h][d] + part[3][h][d];
  }
}

// ---------------- sliding-window attention (all 4 heads in one pass) ----------
__global__ __launch_bounds__(256) void win_attn(const float* __restrict__ Q,
                                                const float* __restrict__ K,
                                                const float* __restrict__ V,
                                                float* __restrict__ Owin) {
  int s = blockIdx.x, g = blockIdx.y;
  __shared__ float q4[4][64];
  __shared__ float p[4][WWIN];
  __shared__ float part[4][4][64];
  int tid = threadIdx.x;
  int base = s - (WWIN - 1);
  {
    int h = tid >> 6, d = tid & 63;
    q4[h][d] = Q[(size_t)(s * H + g * HPG + h) * 64 + d];
  }
  __syncthreads();

  float acc[2][4];
#pragma unroll
  for (int r = 0; r < 2; ++r)
#pragma unroll
    for (int h = 0; h < 4; ++h) acc[r][h] = 0.f;
  int u_[2];
  bool ok[2];
#pragma unroll
  for (int r = 0; r < 2; ++r) {
    int u = base + r * 256 + tid;
    ok[r] = (u >= 0);
    u_[r] = ok[r] ? u : 0;
  }
#pragma unroll
  for (int kk = 0; kk < 64; kk += 4) {
    float4 qv[4];
#pragma unroll
    for (int h = 0; h < 4; ++h) qv[h] = *(const float4*)&q4[h][kk];
#pragma unroll
    for (int r = 0; r < 2; ++r) {
      float4 kv = *(const float4*)&K[(size_t)(u_[r] * G + g) * 64 + kk];
#pragma unroll
      for (int h = 0; h < 4; ++h)
        acc[r][h] += qv[h].x * kv.x + qv[h].y * kv.y + qv[h].z * kv.z + qv[h].w * kv.w;
    }
  }
#pragma unroll
  for (int r = 0; r < 2; ++r) {
    int i = r * 256 + tid;
#pragma unroll
    for (int h = 0; h < 4; ++h) p[h][i] = ok[r] ? acc[r][h] * 0.125f : -INFINITY;
  }
  __syncthreads();

  int w = tid >> 6, lane = tid & 63;
  {
    float vals[8];
    float m = -INFINITY;
#pragma unroll
    for (int r = 0; r < 8; ++r) {
      vals[r] = p[w][lane + 64 * r];
      m = fmaxf(m, vals[r]);
    }
    for (int off = 32; off; off >>= 1) m = fmaxf(m, __shfl_xor(m, off));
    float sum = 0.f;
#pragma unroll
    for (int r = 0; r < 8; ++r) {
      float e = (vals[r] > -INFINITY) ? expf(vals[r] - m) : 0.f;
      vals[r] = e;
      sum += e;
    }
    for (int off = 32; off; off >>= 1) sum += __shfl_xor(sum, off);
    float inv = 1.f / sum;  // u=s always visible
#pragma unroll
    for (int r = 0; r < 8; ++r) p[w][lane + 64 * r] = vals[r] * inv;
  }
  __syncthreads();

  int ck = tid >> 6, d = tid & 63;
  float o[4] = {0.f, 0.f, 0.f, 0.f};
  for (int i0 = ck * 128; i0 < ck * 128 + 128; i0 += 4) {
    if (base + i0 + 3 < 0) continue;  // wave-uniform skip
    float4 p0 = *(const float4*)&p[0][i0];
    float4 p1 = *(const float4*)&p[1][i0];
    float4 p2 = *(const float4*)&p[2][i0];
    float4 p3 = *(const float4*)&p[3][i0];
#define WIN_STEP(T, C)                                                      \
    {                                                                       \
      int u = base + i0 + T;                                                \
      if (u >= 0) {                                                         \
        float v = V[(size_t)(u * G + g) * 64 + d];                          \
        o[0] += p0.C * v; o[1] += p1.C * v; o[2] += p2.C * v; o[3] += p3.C * v; \
      }                                                                     \
    }
    WIN_STEP(0, x) WIN_STEP(1, y) WIN_STEP(2, z) WIN_STEP(3, w)
#undef WIN_STEP
  }
#pragma unroll
  for (int h = 0; h < 4; ++h) part[ck][h][d] = o[h];
  __syncthreads();
  {
    int h = tid >> 6;
    Owin[(size_t)(s * H + g * HPG + h) * 64 + d] =
        part[0][h][d] + part[1][h][d] + part[2][h][d] + part[3][h][d];
  }
}

// ---------------- gating MLP ---------------------------------------------------
__global__ void gate_kernel(const float* __restrict__ Q, const float* __restrict__ w1,
                            const float* __restrict__ b1, const float* __restrict__ w2,
                            const float* __restrict__ b2, float* __restrict__ gates) {
  int idx = blockIdx.x * blockDim.x + threadIdx.x;
  if (idx >= S * G) return;
  int s = idx >> 2, g = idx & 3;
  float qm[64];
#pragma unroll
  for (int d = 0; d < 64; ++d) {
    float a = 0.f;
    for (int hp = 0; hp < HPG; ++hp) a += Q[(size_t)(s * H + g * HPG + hp) * 64 + d];
    qm[d] = a * 0.25f;
  }
  float gl[3] = {b2[0], b2[1], b2[2]};
  for (int j = 0; j < GH; ++j) {
    float z = b1[j];
    for (int d = 0; d < 64; ++d) z += qm[d] * w1[d * GH + j];
    float sl = z / (1.f + expf(-z));
    gl[0] += sl * w2[j * 3 + 0];
    gl[1] += sl * w2[j * 3 + 1];
    gl[2] += sl * w2[j * 3 + 2];
  }
  float m = fmaxf(gl[0], fmaxf(gl[1], gl[2]));
  float e0 = expf(gl[0] - m), e1 = expf(gl[1] - m), e2 = expf(gl[2] - m);
  float inv = 1.f / (e0 + e1 + e2);
  float p0 = e0 * inv, p1 = e1 * inv, p2 = e2 * inv;
  int am = (gl[0] >= gl[1] && gl[0] >= gl[2]) ? 0 : ((gl[1] >= gl[2]) ? 1 : 2);
  float t1 = (am == 0) ? fmaxf(gl[1], gl[2]) : ((am == 1) ? fmaxf(gl[0], gl[2]) : fmaxf(gl[0], gl[1]));
  if (m - t1 > 50.f) {
    p0 = (am == 0) ? 1.f : 0.f;
    p1 = (am == 1) ? 1.f : 0.f;
    p2 = (am == 2) ? 1.f : 0.f;
  }
  gates[idx * 3 + 0] = p0;
  gates[idx * 3 + 1] = p1;
  gates[idx * 3 + 2] = p2;
}

// ---------------- combine branches ---------------------------------------------
__global__ void combine(const float* __restrict__ Oc, const float* __restrict__ Os,
                        const float* __restrict__ Ow, const float* __restrict__ gates,
                        float* __restrict__ O) {
  int idx = blockIdx.x * blockDim.x + threadIdx.x;
  if (idx >= S * H * DV) return;
  int h = (idx >> 6) & 15;
  int s = idx >> 10;
  int g = h >> 2;
  const float* gp = &gates[(size_t)(s * G + g) * 3];
  O[idx] = gp[0] * Oc[idx] + gp[1] * Os[idx] + gp[2] * Ow[idx];
}

// ---------------- host launch ---------------------------------------------------
extern "C" void kernel_launch(void* const* d_in, const int* in_sizes, int n_in,
                              void* d_out, int out_size, void* d_ws, size_t ws_size,
                              hipStream_t stream) {
  const float* x = (const float*)d_in[0];
  const float* W_Q = (const float*)d_in[1];
  const float* W_K_sel = (const float*)d_in[2];
  const float* W_V_sel = (const float*)d_in[3];
  const float* W_K_win = (const float*)d_in[4];
  const float* W_V_win = (const float*)d_in[5];
  const float* W_K_cmp = (const float*)d_in[6];
  const float* W_V_cmp = (const float*)d_in[7];
  const float* W_out = (const float*)d_in[8];
  const float* gw1 = (const float*)d_in[9];
  const float* gb1 = (const float*)d_in[10];
  const float* gw2 = (const float*)d_in[11];
  const float* gb2 = (const float*)d_in[12];

  float* w = (float*)d_ws;
  float* cosT = w;  w += S * 32;
  float* sinT = w;  w += S * 32;
  float* Qb   = w;  w += S * H * DK;
  float* Ksel = w;  w += S * G * DK;   // KV block: 6 consecutive S*256 buffers
  float* Vsel = w;  w += S * G * DV;
  float* Kwin = w;  w += S * G * DK;
  float* Vwin = w;  w += S * G * DV;
  float* Kcr  = w;  w += S * G * DK;
  float* Vcr  = w;  w += S * G * DV;
  float* Kc   = w;  w += G * NCMP * DK;
  float* Vc   = w;  w += G * NCMP * DV;
  float* Ocmp = w;  w += S * H * DV;
  float* Osel = w;  w += S * H * DV;
  float* Owin = w;  w += S * H * DV;
  float* gates= w;  w += S * G * 3;
  float* Ocomb= w;  w += S * H * DV;
  unsigned int* selm = (unsigned int*)w;

  rope_table<<<(S * 32 + 255) / 256, 256, 0, stream>>>(cosT, sinT);

  gemm_f32<<<dim3(DIM / 64, S / 64), 256, 0, stream>>>(x, W_Q, Qb, H * DK, DIM);
  gemm_kv<<<dim3(4, S / 64, 6), 256, 0, stream>>>(x, W_K_sel, W_V_sel, W_K_win,
                                                  W_V_win, W_K_cmp, W_V_cmp, Ksel);

  rope_apply<<<(S * H * 32 + 255) / 256, 256, 0, stream>>>(Qb, cosT, sinT, H, S * H * 32);
  rope_apply<<<(S * G * 32 + 255) / 256, 256, 0, stream>>>(Ksel, cosT, sinT, G, S * G * 32);
  rope_apply<<<(S * G * 32 + 255) / 256, 256, 0, stream>>>(Kwin, cosT, sinT, G, S * G * 32);
  rope_apply<<<(S * G * 32 + 255) / 256, 256, 0, stream>>>(Kcr, cosT, sinT, G, S * G * 32);

  pool_cmp<<<dim3(NCMP, G), 64, 0, stream>>>(Kcr, Vcr, Kc, Vc);

  cmp_attn<<<dim3(S, G), 256, 0, stream>>>(Qb, Kc, Vc, Ocmp, selm);
  sel_attn<<<dim3(S, G), 256, 0, stream>>>(Qb, Ksel, Vsel, selm, Osel);
  win_attn<<<dim3(S, G), 256, 0, stream>>>(Qb, Kwin, Vwin, Owin);

  gate_kernel<<<(S * G + 255) / 256, 256, 0, stream>>>(Qb, gw1, gb1, gw2, gb2, gates);
  combine<<<(S * H * DV + 255) / 256, 256, 0, stream>>>(Ocmp, Osel, Owin, gates, Ocomb);

  gemm_f32<<<dim3(DIM / 64, S / 64), 256, 0, stream>>>(Ocomb, W_out, (float*)d_out, DIM, H * DV);
}

// Round 3
// 944.420 us; speedup vs baseline: 2.5202x; 2.1011x over previous
//
#include <hip/hip_runtime.h>
#include <math.h>

#define S 2048
#define DIM 1024
#define H 16
#define G 4
#define HPG 4
#define DK 64
#define DV 64
#define NCMP 127
#define JBLK 32
#define NSEL 16
#define WWIN 512
#define GH 32

// ---------------- RoPE cos/sin table (fp64-accurate, matches np reference) ---
__global__ void rope_table(float* __restrict__ cosT, float* __restrict__ sinT) {
  int idx = blockIdx.x * blockDim.x + threadIdx.x;
  if (idx >= S * 32) return;
  int s = idx >> 5, i = idx & 31;
  double inv = pow(10000.0, -2.0 * (double)i / 64.0);
  double ang = (double)s * inv;
  cosT[idx] = (float)cos(ang);
  sinT[idx] = (float)sin(ang);
}

// ---------------- fp32 tiled GEMM body (64x64 tile, 4x4/thread) --------------
__device__ __forceinline__ void gemm_body(const float* __restrict__ A,
                                          const float* __restrict__ B,
                                          float* __restrict__ C,
                                          int N, int K, int bm, int bn,
                                          float (*As)[64], float (*Bs)[64]) {
  int tid = threadIdx.x;
  int tr = tid >> 4, tc = tid & 15;
  float acc[4][4] = {{0.f}};
  int arow = tid >> 2;
  int acol = (tid & 3) << 2;
  int brow = tid >> 4;
  int bcol = (tid & 15) << 2;
  const float* Ab = A + (size_t)(bm * 64) * K;
  const float* Bb = B + bn * 64;
  for (int k0 = 0; k0 < K; k0 += 16) {
    float4 av = *(const float4*)(Ab + (size_t)arow * K + k0 + acol);
    float4 bv = *(const float4*)(Bb + (size_t)(k0 + brow) * N + bcol);
    As[acol + 0][arow] = av.x;
    As[acol + 1][arow] = av.y;
    As[acol + 2][arow] = av.z;
    As[acol + 3][arow] = av.w;
    *(float4*)(&Bs[brow][bcol]) = bv;
    __syncthreads();
#pragma unroll
    for (int kk = 0; kk < 16; ++kk) {
      float a[4], b[4];
#pragma unroll
      for (int q = 0; q < 4; ++q) {
        a[q] = As[kk][(tr << 2) + q];
        b[q] = Bs[kk][(tc << 2) + q];
      }
#pragma unroll
      for (int i = 0; i < 4; ++i)
#pragma unroll
        for (int jj = 0; jj < 4; ++jj) acc[i][jj] += a[i] * b[jj];
    }
    __syncthreads();
  }
  for (int i = 0; i < 4; ++i)
    for (int jj = 0; jj < 4; ++jj)
      C[(size_t)(bm * 64 + (tr << 2) + i) * N + bn * 64 + (tc << 2) + jj] = acc[i][jj];
}

__global__ __launch_bounds__(256) void gemm_f32(const float* __restrict__ A,
                                                const float* __restrict__ B,
                                                float* __restrict__ C,
                                                int N, int K) {
  __shared__ float As[16][64];
  __shared__ float Bs[16][64];
  gemm_body(A, B, C, N, K, blockIdx.y, blockIdx.x, As, Bs);
}

// batched K/V projections: 6 weight matrices, outputs contiguous (z*S*256)
__global__ __launch_bounds__(256) void gemm_kv(const float* __restrict__ x,
                                               const float* __restrict__ W0,
                                               const float* __restrict__ W1,
                                               const float* __restrict__ W2,
                                               const float* __restrict__ W3,
                                               const float* __restrict__ W4,
                                               const float* __restrict__ W5,
                                               float* __restrict__ out) {
  __shared__ float As[16][64];
  __shared__ float Bs[16][64];
  int z = blockIdx.z;
  const float* B;
  switch (z) {
    case 0: B = W0; break;
    case 1: B = W1; break;
    case 2: B = W2; break;
    case 3: B = W3; break;
    case 4: B = W4; break;
    default: B = W5; break;
  }
  gemm_body(x, B, out + (size_t)z * S * 256, 256, DIM, blockIdx.y, blockIdx.x, As, Bs);
}

// ---------------- in-place RoPE on [S][NH][64] --------------------------------
__global__ void rope_apply(float* __restrict__ a, const float* __restrict__ cosT,
                           const float* __restrict__ sinT, int NH, int total) {
  int idx = blockIdx.x * blockDim.x + threadIdx.x;
  if (idx >= total) return;
  int i = idx & 31;
  int rest = idx >> 5;
  int n = rest % NH;
  int s = rest / NH;
  float c = cosT[s * 32 + i], sn = sinT[s * 32 + i];
  float* base = a + (size_t)(s * NH + n) * 64;
  float x1 = base[i], x2 = base[i + 32];
  base[i] = x1 * c - x2 * sn;
  base[i + 32] = x2 * c + x1 * sn;
}

// ---------------- avg-pool compressed K/V -------------------------------------
__global__ void pool_cmp(const float* __restrict__ Kcr, const float* __restrict__ Vcr,
                         float* __restrict__ Kc, float* __restrict__ Vc) {
  int c = blockIdx.x, g = blockIdx.y, d = threadIdx.x;
  float sk = 0.f, sv = 0.f;
  for (int l = 0; l < 32; ++l) {
    int t = c * 16 + l;
    sk += Kcr[(size_t)(t * G + g) * 64 + d];
    sv += Vcr[(size_t)(t * G + g) * 64 + d];
  }
  Kc[(size_t)(g * NCMP + c) * 64 + d] = sk * (1.f / 32.f);
  Vc[(size_t)(g * NCMP + c) * 64 + d] = sv * (1.f / 32.f);
}

// ---------------- compressed attention + selection top-k ----------------------
__global__ __launch_bounds__(256) void cmp_attn(const float* __restrict__ Q,
                                                const float* __restrict__ Kc,
                                                const float* __restrict__ Vc,
                                                float* __restrict__ Ocmp,
                                                unsigned int* __restrict__ selm) {
  int s = blockIdx.x, g = blockIdx.y;
  __shared__ float q4[4][64];
  __shared__ float sc[4][128];
  __shared__ float pgp[4][JBLK];
  __shared__ float pg[JBLK];
  int tid = threadIdx.x;
  {
    int h = tid >> 6, d = tid & 63;
    q4[h][d] = Q[(size_t)(s * H + g * HPG + h) * 64 + d];
  }
  __syncthreads();

  // scores: one key per thread (tid < 127), all 4 heads
  if (tid < NCMP) {
    int c = tid;
    bool vis = (c * 16 + 32 <= s + 1);
    float a0 = 0.f, a1 = 0.f, a2 = 0.f, a3 = 0.f;
    const float* kr = &Kc[(size_t)(g * NCMP + c) * 64];
#pragma unroll 4
    for (int kk = 0; kk < 16; ++kk) {
      float4 kv = *(const float4*)&kr[kk * 4];
      float4 q0 = *(const float4*)&q4[0][kk * 4];
      float4 q1 = *(const float4*)&q4[1][kk * 4];
      float4 q2 = *(const float4*)&q4[2][kk * 4];
      float4 q3 = *(const float4*)&q4[3][kk * 4];
      a0 += q0.x * kv.x + q0.y * kv.y + q0.z * kv.z + q0.w * kv.w;
      a1 += q1.x * kv.x + q1.y * kv.y + q1.z * kv.z + q1.w * kv.w;
      a2 += q2.x * kv.x + q2.y * kv.y + q2.z * kv.z + q2.w * kv.w;
      a3 += q3.x * kv.x + q3.y * kv.y + q3.z * kv.z + q3.w * kv.w;
    }
    sc[0][c] = vis ? a0 * 0.125f : -INFINITY;
    sc[1][c] = vis ? a1 * 0.125f : -INFINITY;
    sc[2][c] = vis ? a2 * 0.125f : -INFINITY;
    sc[3][c] = vis ? a3 * 0.125f : -INFINITY;
  }
  __syncthreads();

  // softmax per head (wave w = head)
  int w = tid >> 6, lane = tid & 63;
  {
    float v0 = sc[w][lane];
    float v1 = (lane + 64 < NCMP) ? sc[w][lane + 64] : -INFINITY;
    float m = fmaxf(v0, v1);
    for (int off = 32; off; off >>= 1) m = fmaxf(m, __shfl_xor(m, off));
    float e0 = (m > -INFINITY && v0 > -INFINITY) ? expf(v0 - m) : 0.f;
    float e1 = (m > -INFINITY && v1 > -INFINITY) ? expf(v1 - m) : 0.f;
    float sum = e0 + e1;
    for (int off = 32; off; off >>= 1) sum += __shfl_xor(sum, off);
    float inv = (sum > 0.f) ? 1.f / sum : 0.f;
    sc[w][lane] = e0 * inv;
    if (lane + 64 < NCMP) sc[w][lane + 64] = e1 * inv;
  }
  __syncthreads();

  // O_cmp = p @ V_cmp
  {
    int h = tid >> 6, d = tid & 63;
    float o = 0.f;
#pragma unroll 4
    for (int c = 0; c < NCMP; ++c) o += sc[h][c] * Vc[(size_t)(g * NCMP + c) * 64 + d];
    Ocmp[(size_t)(s * H + g * HPG + h) * 64 + d] = o;
  }

  // p_grp: overlap-weighted map to selection blocks, summed over heads
  if (tid < 128) {
    int h = tid >> 5, j = tid & 31;
    float a = 0.f;
    for (int c = 0; c < NCMP; ++c) {
      int lo = max(c * 16, j * 64);
      int hi = min(c * 16 + 32, j * 64 + 64);
      if (hi > lo) a += sc[h][c] * (float)(hi - lo) * (1.f / 32.f);
    }
    pgp[h][j] = a;
  }
  __syncthreads();
  if (tid < JBLK) pg[tid] = pgp[0][tid] + pgp[1][tid] + pgp[2][tid] + pgp[3][tid];
  __syncthreads();

  if (tid == 0) {
    float scj[JBLK];
    int cur = s >> 6;
    for (int j = 0; j < JBLK; ++j) {
      float v = (j * 64 <= s) ? pg[j] : -1e30f;
      if (j == 0 || j == cur) v = 1e9f;
      scj[j] = v;
    }
    unsigned int mask = 0;
    for (int n = 0; n < NSEL; ++n) {
      int bi = 0;
      float bv = -INFINITY;
      for (int j = 0; j < JBLK; ++j)
        if (scj[j] > bv) { bv = scj[j]; bi = j; }
      mask |= 1u << bi;
      scj[bi] = -INFINITY;
    }
    selm[s * G + g] = mask;
  }
}

// ---------------- selection attention (4 heads/pass, low reg pressure) --------
__global__ __launch_bounds__(256) void sel_attn(const float* __restrict__ Q,
                                                const float* __restrict__ K,
                                                const float* __restrict__ V,
                                                const unsigned int* __restrict__ selm,
                                                float* __restrict__ Osel) {
  int s = blockIdx.x, g = blockIdx.y;
  __shared__ float q4[4][64];
  __shared__ float p[4][1024];
  __shared__ float part[4][4][64];
  __shared__ int blks[NSEL];
  int tid = threadIdx.x;
  if (tid == 0) {
    unsigned int m = selm[s * G + g];
    int n = 0;
    for (int j = 0; j < JBLK && n < NSEL; ++j)
      if ((m >> j) & 1u) blks[n++] = j;
  }
  {
    int h = tid >> 6, d = tid & 63;
    q4[h][d] = Q[(size_t)(s * H + g * HPG + h) * 64 + d];
  }
  __syncthreads();

  // ---- scores: one key-row at a time, K row reused for 4 heads ----
#pragma unroll 1
  for (int r = 0; r < 4; ++r) {
    int i = r * 256 + tid;
    int u = blks[i >> 6] * 64 + (i & 63);
    bool ok = (u <= s);
    const float4* kp = (const float4*)&K[(size_t)(u * G + g) * 64];
    float a0 = 0.f, a1 = 0.f, a2 = 0.f, a3 = 0.f;
#pragma unroll 4
    for (int kk = 0; kk < 16; ++kk) {
      float4 kv = kp[kk];
      float4 q0 = *(const float4*)&q4[0][kk * 4];
      float4 q1 = *(const float4*)&q4[1][kk * 4];
      float4 q2 = *(const float4*)&q4[2][kk * 4];
      float4 q3 = *(const float4*)&q4[3][kk * 4];
      a0 += q0.x * kv.x + q0.y * kv.y + q0.z * kv.z + q0.w * kv.w;
      a1 += q1.x * kv.x + q1.y * kv.y + q1.z * kv.z + q1.w * kv.w;
      a2 += q2.x * kv.x + q2.y * kv.y + q2.z * kv.z + q2.w * kv.w;
      a3 += q3.x * kv.x + q3.y * kv.y + q3.z * kv.z + q3.w * kv.w;
    }
    p[0][i] = ok ? a0 * 0.125f : -INFINITY;
    p[1][i] = ok ? a1 * 0.125f : -INFINITY;
    p[2][i] = ok ? a2 * 0.125f : -INFINITY;
    p[3][i] = ok ? a3 * 0.125f : -INFINITY;
  }
  __syncthreads();

  // ---- softmax: wave w handles head w ----
  int w = tid >> 6, lane = tid & 63;
  {
    float vals[16];
    float m = -INFINITY;
#pragma unroll
    for (int r = 0; r < 16; ++r) {
      vals[r] = p[w][lane + 64 * r];
      m = fmaxf(m, vals[r]);
    }
    for (int off = 32; off; off >>= 1) m = fmaxf(m, __shfl_xor(m, off));
    float sum = 0.f;
#pragma unroll
    for (int r = 0; r < 16; ++r) {
      float e = (vals[r] > -INFINITY) ? expf(vals[r] - m) : 0.f;
      vals[r] = e;
      sum += e;
    }
    for (int off = 32; off; off >>= 1) sum += __shfl_xor(sum, off);
    float inv = 1.f / sum;  // current token always visible -> sum > 0
#pragma unroll
    for (int r = 0; r < 16; ++r) p[w][lane + 64 * r] = vals[r] * inv;
  }
  __syncthreads();

  // ---- PV: V element loaded once, reused for 4 heads (ck wave-uniform) ----
  int ck = tid >> 6, d = tid & 63;
  float o0 = 0.f, o1 = 0.f, o2 = 0.f, o3 = 0.f;
#pragma unroll 2
  for (int i0 = ck * 256; i0 < ck * 256 + 256; i0 += 4) {
    float4 p0 = *(const float4*)&p[0][i0];
    float4 p1 = *(const float4*)&p[1][i0];
    float4 p2 = *(const float4*)&p[2][i0];
    float4 p3 = *(const float4*)&p[3][i0];
#define SEL_STEP(T, C)                                                        \
    {                                                                         \
      int i = i0 + T;                                                         \
      int u = blks[i >> 6] * 64 + (i & 63);                                   \
      float v = V[(size_t)(u * G + g) * 64 + d];                              \
      o0 += p0.C * v; o1 += p1.C * v; o2 += p2.C * v; o3 += p3.C * v;         \
    }
    SEL_STEP(0, x) SEL_STEP(1, y) SEL_STEP(2, z) SEL_STEP(3, w)
#undef SEL_STEP
  }
  part[ck][0][d] = o0;
  part[ck][1][d] = o1;
  part[ck][2][d] = o2;
  part[ck][3][d] = o3;
  __syncthreads();
  {
    int h = tid >> 6;
    Osel[(size_t)(s * H + g * HPG + h) * 64 + d] =
        part[0][h][d] + part[1][h][d] + part[2][h][d] + part[3][h][d];
  }
}

// ---------------- sliding-window attention (same discipline) ------------------
__global__ __launch_bounds__(256) void win_attn(const float* __restrict__ Q,
                                                const float* __restrict__ K,
                                                const float* __restrict__ V,
                                                float* __restrict__ Owin) {
  int s = blockIdx.x, g = blockIdx.y;
  __shared__ float q4[4][64];
  __shared__ float p[4][WWIN];
  __shared__ float part[4][4][64];
  int tid = threadIdx.x;
  int base = s - (WWIN - 1);
  {
    int h = tid >> 6, d = tid & 63;
    q4[h][d] = Q[(size_t)(s * H + g * HPG + h) * 64 + d];
  }
  __syncthreads();

#pragma unroll 1
  for (int r = 0; r < 2; ++r) {
    int i = r * 256 + tid;
    int u = base + i;
    bool ok = (u >= 0);
    const float4* kp = (const float4*)&K[(size_t)((ok ? u : 0) * G + g) * 64];
    float a0 = 0.f, a1 = 0.f, a2 = 0.f, a3 = 0.f;
#pragma unroll 4
    for (int kk = 0; kk < 16; ++kk) {
      float4 kv = kp[kk];
      float4 q0 = *(const float4*)&q4[0][kk * 4];
      float4 q1 = *(const float4*)&q4[1][kk * 4];
      float4 q2 = *(const float4*)&q4[2][kk * 4];
      float4 q3 = *(const float4*)&q4[3][kk * 4];
      a0 += q0.x * kv.x + q0.y * kv.y + q0.z * kv.z + q0.w * kv.w;
      a1 += q1.x * kv.x + q1.y * kv.y + q1.z * kv.z + q1.w * kv.w;
      a2 += q2.x * kv.x + q2.y * kv.y + q2.z * kv.z + q2.w * kv.w;
      a3 += q3.x * kv.x + q3.y * kv.y + q3.z * kv.z + q3.w * kv.w;
    }
    p[0][i] = ok ? a0 * 0.125f : -INFINITY;
    p[1][i] = ok ? a1 * 0.125f : -INFINITY;
    p[2][i] = ok ? a2 * 0.125f : -INFINITY;
    p[3][i] = ok ? a3 * 0.125f : -INFINITY;
  }
  __syncthreads();

  int w = tid >> 6, lane = tid & 63;
  {
    float vals[8];
    float m = -INFINITY;
#pragma unroll
    for (int r = 0; r < 8; ++r) {
      vals[r] = p[w][lane + 64 * r];
      m = fmaxf(m, vals[r]);
    }
    for (int off = 32; off; off >>= 1) m = fmaxf(m, __shfl_xor(m, off));
    float sum = 0.f;
#pragma unroll
    for (int r = 0; r < 8; ++r) {
      float e = (vals[r] > -INFINITY) ? expf(vals[r] - m) : 0.f;
      vals[r] = e;
      sum += e;
    }
    for (int off = 32; off; off >>= 1) sum += __shfl_xor(sum, off);
    float inv = 1.f / sum;  // u=s always visible
#pragma unroll
    for (int r = 0; r < 8; ++r) p[w][lane + 64 * r] = vals[r] * inv;
  }
  __syncthreads();

  int ck = tid >> 6, d = tid & 63;
  float o0 = 0.f, o1 = 0.f, o2 = 0.f, o3 = 0.f;
#pragma unroll 2
  for (int i0 = ck * 128; i0 < ck * 128 + 128; i0 += 4) {
    if (base + i0 + 3 < 0) continue;  // wave-uniform skip
    float4 p0 = *(const float4*)&p[0][i0];
    float4 p1 = *(const float4*)&p[1][i0];
    float4 p2 = *(const float4*)&p[2][i0];
    float4 p3 = *(const float4*)&p[3][i0];
#define WIN_STEP(T, C)                                                        \
    {                                                                         \
      int u = base + i0 + T;                                                  \
      if (u >= 0) {                                                           \
        float v = V[(size_t)(u * G + g) * 64 + d];                            \
        o0 += p0.C * v; o1 += p1.C * v; o2 += p2.C * v; o3 += p3.C * v;       \
      }                                                                       \
    }
    WIN_STEP(0, x) WIN_STEP(1, y) WIN_STEP(2, z) WIN_STEP(3, w)
#undef WIN_STEP
  }
  part[ck][0][d] = o0;
  part[ck][1][d] = o1;
  part[ck][2][d] = o2;
  part[ck][3][d] = o3;
  __syncthreads();
  {
    int h = tid >> 6;
    Owin[(size_t)(s * H + g * HPG + h) * 64 + d] =
        part[0][h][d] + part[1][h][d] + part[2][h][d] + part[3][h][d];
  }
}

// ---------------- gating MLP ---------------------------------------------------
__global__ void gate_kernel(const float* __restrict__ Q, const float* __restrict__ w1,
                            const float* __restrict__ b1, const float* __restrict__ w2,
                            const float* __restrict__ b2, float* __restrict__ gates) {
  int idx = blockIdx.x * blockDim.x + threadIdx.x;
  if (idx >= S * G) return;
  int s = idx >> 2, g = idx & 3;
  float qm[64];
#pragma unroll
  for (int d = 0; d < 64; ++d) {
    float a = 0.f;
    for (int hp = 0; hp < HPG; ++hp) a += Q[(size_t)(s * H + g * HPG + hp) * 64 + d];
    qm[d] = a * 0.25f;
  }
  float gl[3] = {b2[0], b2[1], b2[2]};
  for (int j = 0; j < GH; ++j) {
    float z = b1[j];
    for (int d = 0; d < 64; ++d) z += qm[d] * w1[d * GH + j];
    float sl = z / (1.f + expf(-z));
    gl[0] += sl * w2[j * 3 + 0];
    gl[1] += sl * w2[j * 3 + 1];
    gl[2] += sl * w2[j * 3 + 2];
  }
  float m = fmaxf(gl[0], fmaxf(gl[1], gl[2]));
  float e0 = expf(gl[0] - m), e1 = expf(gl[1] - m), e2 = expf(gl[2] - m);
  float inv = 1.f / (e0 + e1 + e2);
  float p0 = e0 * inv, p1 = e1 * inv, p2 = e2 * inv;
  int am = (gl[0] >= gl[1] && gl[0] >= gl[2]) ? 0 : ((gl[1] >= gl[2]) ? 1 : 2);
  float t1 = (am == 0) ? fmaxf(gl[1], gl[2]) : ((am == 1) ? fmaxf(gl[0], gl[2]) : fmaxf(gl[0], gl[1]));
  if (m - t1 > 50.f) {
    p0 = (am == 0) ? 1.f : 0.f;
    p1 = (am == 1) ? 1.f : 0.f;
    p2 = (am == 2) ? 1.f : 0.f;
  }
  gates[idx * 3 + 0] = p0;
  gates[idx * 3 + 1] = p1;
  gates[idx * 3 + 2] = p2;
}

// ---------------- combine branches ---------------------------------------------
__global__ void combine(const float* __restrict__ Oc, const float* __restrict__ Os,
                        const float* __restrict__ Ow, const float* __restrict__ gates,
                        float* __restrict__ O) {
  int idx = blockIdx.x * blockDim.x + threadIdx.x;
  if (idx >= S * H * DV) return;
  int h = (idx >> 6) & 15;
  int s = idx >> 10;
  int g = h >> 2;
  const float* gp = &gates[(size_t)(s * G + g) * 3];
  O[idx] = gp[0] * Oc[idx] + gp[1] * Os[idx] + gp[2] * Ow[idx];
}

// ---------------- host launch ---------------------------------------------------
extern "C" void kernel_launch(void* const* d_in, const int* in_sizes, int n_in,
                              void* d_out, int out_size, void* d_ws, size_t ws_size,
                              hipStream_t stream) {
  const float* x = (const float*)d_in[0];
  const float* W_Q = (const float*)d_in[1];
  const float* W_K_sel = (const float*)d_in[2];
  const float* W_V_sel = (const float*)d_in[3];
  const float* W_K_win = (const float*)d_in[4];
  const float* W_V_win = (const float*)d_in[5];
  const float* W_K_cmp = (const float*)d_in[6];
  const float* W_V_cmp = (const float*)d_in[7];
  const float* W_out = (const float*)d_in[8];
  const float* gw1 = (const float*)d_in[9];
  const float* gb1 = (const float*)d_in[10];
  const float* gw2 = (const float*)d_in[11];
  const float* gb2 = (const float*)d_in[12];

  float* w = (float*)d_ws;
  float* cosT = w;  w += S * 32;
  float* sinT = w;  w += S * 32;
  float* Qb   = w;  w += S * H * DK;
  float* Ksel = w;  w += S * G * DK;   // KV block: 6 consecutive S*256 buffers
  float* Vsel = w;  w += S * G * DV;
  float* Kwin = w;  w += S * G * DK;
  float* Vwin = w;  w += S * G * DV;
  float* Kcr  = w;  w += S * G * DK;
  float* Vcr  = w;  w += S * G * DV;
  float* Kc   = w;  w += G * NCMP * DK;
  float* Vc   = w;  w += G * NCMP * DV;
  float* Ocmp = w;  w += S * H * DV;
  float* Osel = w;  w += S * H * DV;
  float* Owin = w;  w += S * H * DV;
  float* gates= w;  w += S * G * 3;
  float* Ocomb= w;  w += S * H * DV;
  unsigned int* selm = (unsigned int*)w;

  rope_table<<<(S * 32 + 255) / 256, 256, 0, stream>>>(cosT, sinT);

  gemm_f32<<<dim3(DIM / 64, S / 64), 256, 0, stream>>>(x, W_Q, Qb, H * DK, DIM);
  gemm_kv<<<dim3(4, S / 64, 6), 256, 0, stream>>>(x, W_K_sel, W_V_sel, W_K_win,
                                                  W_V_win, W_K_cmp, W_V_cmp, Ksel);

  rope_apply<<<(S * H * 32 + 255) / 256, 256, 0, stream>>>(Qb, cosT, sinT, H, S * H * 32);
  rope_apply<<<(S * G * 32 + 255) / 256, 256, 0, stream>>>(Ksel, cosT, sinT, G, S * G * 32);
  rope_apply<<<(S * G * 32 + 255) / 256, 256, 0, stream>>>(Kwin, cosT, sinT, G, S * G * 32);
  rope_apply<<<(S * G * 32 + 255) / 256, 256, 0, stream>>>(Kcr, cosT, sinT, G, S * G * 32);

  pool_cmp<<<dim3(NCMP, G), 64, 0, stream>>>(Kcr, Vcr, Kc, Vc);

  cmp_attn<<<dim3(S, G), 256, 0, stream>>>(Qb, Kc, Vc, Ocmp, selm);
  sel_attn<<<dim3(S, G), 256, 0, stream>>>(Qb, Ksel, Vsel, selm, Osel);
  win_attn<<<dim3(S, G), 256, 0, stream>>>(Qb, Kwin, Vwin, Owin);

  gate_kernel<<<(S * G + 255) / 256, 256, 0, stream>>>(Qb, gw1, gb1, gw2, gb2, gates);
  combine<<<(S * H * DV + 255) / 256, 256, 0, stream>>>(Ocmp, Osel, Owin, gates, Ocomb);

  gemm_f32<<<dim3(DIM / 64, S / 64), 256, 0, stream>>>(Ocomb, W_out, (float*)d_out, DIM, H * DV);
}

// Round 4
// 675.741 us; speedup vs baseline: 3.5222x; 1.3976x over previous
//
#include <hip/hip_runtime.h>
#include <math.h>

#define S 2048
#define DIM 1024
#define H 16
#define G 4
#define HPG 4
#define DK 64
#define DV 64
#define NCMP 127
#define JBLK 32
#define NSEL 16
#define WWIN 512
#define GH 32

typedef __attribute__((ext_vector_type(8))) __bf16 bf16x8;
typedef __attribute__((ext_vector_type(4))) float f32x4;

__device__ __forceinline__ unsigned short f2bf(float f) {
  unsigned u = __float_as_uint(f);
  unsigned r = (u + 0x7FFFu + ((u >> 16) & 1u)) >> 16;
  return (unsigned short)r;
}

__device__ __forceinline__ f32x4 mfma16(bf16x8 a, bf16x8 b, f32x4 c) {
  return __builtin_amdgcn_mfma_f32_16x16x32_bf16(a, b, c, 0, 0, 0);
}

// ---------------- RoPE cos/sin table (fp64-accurate, matches np reference) ---
__global__ void rope_table(float* __restrict__ cosT, float* __restrict__ sinT) {
  int idx = blockIdx.x * blockDim.x + threadIdx.x;
  if (idx >= S * 32) return;
  int s = idx >> 5, i = idx & 31;
  double inv = pow(10000.0, -2.0 * (double)i / 64.0);
  double ang = (double)s * inv;
  cosT[idx] = (float)cos(ang);
  sinT[idx] = (float)sin(ang);
}

// ---------------- fp32 tiled GEMM body (64x64 tile, 4x4/thread) --------------
__device__ __forceinline__ void gemm_body(const float* __restrict__ A,
                                          const float* __restrict__ B,
                                          float* __restrict__ C,
                                          int N, int K, int bm, int bn,
                                          float (*As)[64], float (*Bs)[64]) {
  int tid = threadIdx.x;
  int tr = tid >> 4, tc = tid & 15;
  float acc[4][4] = {{0.f}};
  int arow = tid >> 2;
  int acol = (tid & 3) << 2;
  int brow = tid >> 4;
  int bcol = (tid & 15) << 2;
  const float* Ab = A + (size_t)(bm * 64) * K;
  const float* Bb = B + bn * 64;
  for (int k0 = 0; k0 < K; k0 += 16) {
    float4 av = *(const float4*)(Ab + (size_t)arow * K + k0 + acol);
    float4 bv = *(const float4*)(Bb + (size_t)(k0 + brow) * N + bcol);
    As[acol + 0][arow] = av.x;
    As[acol + 1][arow] = av.y;
    As[acol + 2][arow] = av.z;
    As[acol + 3][arow] = av.w;
    *(float4*)(&Bs[brow][bcol]) = bv;
    __syncthreads();
#pragma unroll
    for (int kk = 0; kk < 16; ++kk) {
      float a[4], b[4];
#pragma unroll
      for (int q = 0; q < 4; ++q) {
        a[q] = As[kk][(tr << 2) + q];
        b[q] = Bs[kk][(tc << 2) + q];
      }
#pragma unroll
      for (int i = 0; i < 4; ++i)
#pragma unroll
        for (int jj = 0; jj < 4; ++jj) acc[i][jj] += a[i] * b[jj];
    }
    __syncthreads();
  }
  for (int i = 0; i < 4; ++i)
    for (int jj = 0; jj < 4; ++jj)
      C[(size_t)(bm * 64 + (tr << 2) + i) * N + bn * 64 + (tc << 2) + jj] = acc[i][jj];
}

__global__ __launch_bounds__(256) void gemm_f32(const float* __restrict__ A,
                                                const float* __restrict__ B,
                                                float* __restrict__ C,
                                                int N, int K) {
  __shared__ float As[16][64];
  __shared__ float Bs[16][64];
  gemm_body(A, B, C, N, K, blockIdx.y, blockIdx.x, As, Bs);
}

__global__ __launch_bounds__(256) void gemm_kv(const float* __restrict__ x,
                                               const float* __restrict__ W0,
                                               const float* __restrict__ W1,
                                               const float* __restrict__ W2,
                                               const float* __restrict__ W3,
                                               const float* __restrict__ W4,
                                               const float* __restrict__ W5,
                                               float* __restrict__ out) {
  __shared__ float As[16][64];
  __shared__ float Bs[16][64];
  int z = blockIdx.z;
  const float* B;
  switch (z) {
    case 0: B = W0; break;
    case 1: B = W1; break;
    case 2: B = W2; break;
    case 3: B = W3; break;
    case 4: B = W4; break;
    default: B = W5; break;
  }
  gemm_body(x, B, out + (size_t)z * S * 256, 256, DIM, blockIdx.y, blockIdx.x, As, Bs);
}

// ---------------- in-place RoPE on [S][NH][64] --------------------------------
__global__ void rope_apply(float* __restrict__ a, const float* __restrict__ cosT,
                           const float* __restrict__ sinT, int NH, int total) {
  int idx = blockIdx.x * blockDim.x + threadIdx.x;
  if (idx >= total) return;
  int i = idx & 31;
  int rest = idx >> 5;
  int n = rest % NH;
  int s = rest / NH;
  float c = cosT[s * 32 + i], sn = sinT[s * 32 + i];
  float* base = a + (size_t)(s * NH + n) * 64;
  float x1 = base[i], x2 = base[i + 32];
  base[i] = x1 * c - x2 * sn;
  base[i + 32] = x2 * c + x1 * sn;
}

// ---------------- avg-pool compressed K/V -------------------------------------
__global__ void pool_cmp(const float* __restrict__ Kcr, const float* __restrict__ Vcr,
                         float* __restrict__ Kc, float* __restrict__ Vc) {
  int c = blockIdx.x, g = blockIdx.y, d = threadIdx.x;
  float sk = 0.f, sv = 0.f;
  for (int l = 0; l < 32; ++l) {
    int t = c * 16 + l;
    sk += Kcr[(size_t)(t * G + g) * 64 + d];
    sv += Vcr[(size_t)(t * G + g) * 64 + d];
  }
  Kc[(size_t)(g * NCMP + c) * 64 + d] = sk * (1.f / 32.f);
  Vc[(size_t)(g * NCMP + c) * 64 + d] = sv * (1.f / 32.f);
}

// ---------------- compressed attention + selection top-k (fp32, exact) --------
__global__ __launch_bounds__(256) void cmp_attn(const float* __restrict__ Q,
                                                const float* __restrict__ Kc,
                                                const float* __restrict__ Vc,
                                                float* __restrict__ Ocmp,
                                                unsigned int* __restrict__ selm) {
  int s = blockIdx.x, g = blockIdx.y;
  __shared__ float q4[4][64];
  __shared__ float sc[4][128];
  __shared__ float pgp[4][JBLK];
  __shared__ float pg[JBLK];
  int tid = threadIdx.x;
  {
    int h = tid >> 6, d = tid & 63;
    q4[h][d] = Q[(size_t)(s * H + g * HPG + h) * 64 + d];
  }
  __syncthreads();

  if (tid < NCMP) {
    int c = tid;
    bool vis = (c * 16 + 32 <= s + 1);
    float a0 = 0.f, a1 = 0.f, a2 = 0.f, a3 = 0.f;
    const float* kr = &Kc[(size_t)(g * NCMP + c) * 64];
#pragma unroll 4
    for (int kk = 0; kk < 16; ++kk) {
      float4 kv = *(const float4*)&kr[kk * 4];
      float4 q0 = *(const float4*)&q4[0][kk * 4];
      float4 q1 = *(const float4*)&q4[1][kk * 4];
      float4 q2 = *(const float4*)&q4[2][kk * 4];
      float4 q3 = *(const float4*)&q4[3][kk * 4];
      a0 += q0.x * kv.x + q0.y * kv.y + q0.z * kv.z + q0.w * kv.w;
      a1 += q1.x * kv.x + q1.y * kv.y + q1.z * kv.z + q1.w * kv.w;
      a2 += q2.x * kv.x + q2.y * kv.y + q2.z * kv.z + q2.w * kv.w;
      a3 += q3.x * kv.x + q3.y * kv.y + q3.z * kv.z + q3.w * kv.w;
    }
    sc[0][c] = vis ? a0 * 0.125f : -INFINITY;
    sc[1][c] = vis ? a1 * 0.125f : -INFINITY;
    sc[2][c] = vis ? a2 * 0.125f : -INFINITY;
    sc[3][c] = vis ? a3 * 0.125f : -INFINITY;
  }
  __syncthreads();

  int w = tid >> 6, lane = tid & 63;
  {
    float v0 = sc[w][lane];
    float v1 = (lane + 64 < NCMP) ? sc[w][lane + 64] : -INFINITY;
    float m = fmaxf(v0, v1);
    for (int off = 32; off; off >>= 1) m = fmaxf(m, __shfl_xor(m, off));
    float e0 = (m > -INFINITY && v0 > -INFINITY) ? expf(v0 - m) : 0.f;
    float e1 = (m > -INFINITY && v1 > -INFINITY) ? expf(v1 - m) : 0.f;
    float sum = e0 + e1;
    for (int off = 32; off; off >>= 1) sum += __shfl_xor(sum, off);
    float inv = (sum > 0.f) ? 1.f / sum : 0.f;
    sc[w][lane] = e0 * inv;
    if (lane + 64 < NCMP) sc[w][lane + 64] = e1 * inv;
  }
  __syncthreads();

  {
    int h = tid >> 6, d = tid & 63;
    float o = 0.f;
#pragma unroll 4
    for (int c = 0; c < NCMP; ++c) o += sc[h][c] * Vc[(size_t)(g * NCMP + c) * 64 + d];
    Ocmp[(size_t)(s * H + g * HPG + h) * 64 + d] = o;
  }

  if (tid < 128) {
    int h = tid >> 5, j = tid & 31;
    float a = 0.f;
    for (int c = 0; c < NCMP; ++c) {
      int lo = max(c * 16, j * 64);
      int hi = min(c * 16 + 32, j * 64 + 64);
      if (hi > lo) a += sc[h][c] * (float)(hi - lo) * (1.f / 32.f);
    }
    pgp[h][j] = a;
  }
  __syncthreads();
  if (tid < JBLK) pg[tid] = pgp[0][tid] + pgp[1][tid] + pgp[2][tid] + pgp[3][tid];
  __syncthreads();

  if (tid == 0) {
    float scj[JBLK];
    int cur = s >> 6;
    for (int j = 0; j < JBLK; ++j) {
      float v = (j * 64 <= s) ? pg[j] : -1e30f;
      if (j == 0 || j == cur) v = 1e9f;
      scj[j] = v;
    }
    unsigned int mask = 0;
    for (int n = 0; n < NSEL; ++n) {
      int bi = 0;
      float bv = -INFINITY;
      for (int j = 0; j < JBLK; ++j)
        if (scj[j] > bv) { bv = scj[j]; bi = j; }
      mask |= 1u << bi;
      scj[bi] = -INFINITY;
    }
    selm[s * G + g] = mask;
  }
}

// ---------------- MFMA flash attention for sel (MODE 0) / win (MODE 1) --------
// block = (64-token tile, group); 4 waves = 4 heads.
template <int MODE>
__global__ __launch_bounds__(256) void attn_mfma(const float* __restrict__ Q,
                                                 const float* __restrict__ K,
                                                 const float* __restrict__ V,
                                                 const unsigned int* __restrict__ selm,
                                                 float* __restrict__ O) {
  __shared__ unsigned short Kl[64 * 64];     // [key][dim], swizzled
  __shared__ unsigned short Vt[64 * 64];     // [dim][key], swizzled
  __shared__ unsigned short Pl[4][64 * 64];  // per wave: [token][key], swizzled
  __shared__ unsigned int sel_l[64];
  __shared__ int blist[JBLK];
  __shared__ int nB_s;

  int t0 = blockIdx.x * 64;
  int g = blockIdx.y;
  int tid = threadIdx.x;
  int w = tid >> 6, lane = tid & 63;
  int l15 = lane & 15, lg = lane >> 4;
  int rswz = (l15 & 7) << 3;  // row-XOR swizzle for fragment reads

  if (MODE == 0) {
    if (tid < 64) sel_l[tid] = selm[(t0 + tid) * G + g];
  }
  __syncthreads();
  if (tid == 0) {
    int n = 0;
    if (MODE == 0) {
      unsigned int un = 0;
      for (int i = 0; i < 64; ++i) un |= sel_l[i];
      for (int j = 0; j < JBLK; ++j)
        if ((un >> j) & 1u) blist[n++] = j;
    } else {
      int jt = t0 >> 6;
      int j0 = jt - 8;
      if (j0 < 0) j0 = 0;
      for (int j = j0; j <= jt; ++j) blist[n++] = j;
    }
    nB_s = n;
  }
  __syncthreads();
  int nB = nB_s;

  // Q fragments (B operand): [nt][kc], token = nt*16+l15, dims kc*32+lg*8..+7
  bf16x8 qf[4][2];
#pragma unroll
  for (int nt = 0; nt < 4; ++nt) {
    const float* qb =
        Q + ((size_t)(t0 + nt * 16 + l15) * H + g * HPG + w) * 64 + lg * 8;
#pragma unroll
    for (int kc = 0; kc < 2; ++kc) {
      float4 a = *(const float4*)(qb + kc * 32);
      float4 b = *(const float4*)(qb + kc * 32 + 4);
      union { unsigned short us[8]; bf16x8 v; } u;
      u.us[0] = f2bf(a.x); u.us[1] = f2bf(a.y); u.us[2] = f2bf(a.z); u.us[3] = f2bf(a.w);
      u.us[4] = f2bf(b.x); u.us[5] = f2bf(b.y); u.us[6] = f2bf(b.z); u.us[7] = f2bf(b.w);
      qf[nt][kc] = u.v;
    }
  }

  float mrun[4], lrun[4];
  f32x4 oacc[4][4];  // [dt][nt]
#pragma unroll
  for (int nt = 0; nt < 4; ++nt) {
    mrun[nt] = -INFINITY;
    lrun[nt] = 0.f;
#pragma unroll
    for (int dt = 0; dt < 4; ++dt) oacc[dt][nt] = (f32x4){0.f, 0.f, 0.f, 0.f};
  }

  for (int b = 0; b < nB; ++b) {
    int j = blist[b];
    int ku = j * 64;

    // ---- stage K [key][dim] ----
    {
      int key = tid >> 2, d0 = (tid & 3) * 16;
      const float* kr = K + ((size_t)(ku + key) * G + g) * 64 + d0;
      union { unsigned short us[16]; float4 f4[2]; } t;
#pragma unroll
      for (int i = 0; i < 4; ++i) {
        float4 v = *(const float4*)(kr + i * 4);
        t.us[i * 4 + 0] = f2bf(v.x);
        t.us[i * 4 + 1] = f2bf(v.y);
        t.us[i * 4 + 2] = f2bf(v.z);
        t.us[i * 4 + 3] = f2bf(v.w);
      }
      int base = key * 64 + d0, swz = (key & 7) << 3;
      *(float4*)&Kl[(base) ^ swz] = t.f4[0];
      *(float4*)&Kl[(base + 8) ^ swz] = t.f4[1];
    }
    // ---- stage V transposed [dim][key] ----
    {
      int dim = tid >> 2, k0 = (tid & 3) * 16;
      union { unsigned short us[16]; float4 f4[2]; } t;
#pragma unroll
      for (int i = 0; i < 16; ++i)
        t.us[i] = f2bf(V[((size_t)(ku + k0 + i) * G + g) * 64 + dim]);
      int base = dim * 64 + k0, swz = (dim & 7) << 3;
      *(float4*)&Vt[(base) ^ swz] = t.f4[0];
      *(float4*)&Vt[(base + 8) ^ swz] = t.f4[1];
    }
    __syncthreads();

    // ---- S^T = mfma(K, Q): D[m=key][n=token] ----
    f32x4 sf[4][4];  // [kt][nt]
#pragma unroll
    for (int kt = 0; kt < 4; ++kt)
#pragma unroll
      for (int nt = 0; nt < 4; ++nt) sf[kt][nt] = (f32x4){0.f, 0.f, 0.f, 0.f};
#pragma unroll
    for (int kt = 0; kt < 4; ++kt) {
      int krow = kt * 16 + l15;
      bf16x8 kf0 = *(const bf16x8*)&Kl[(krow * 64 + lg * 8) ^ rswz];
      bf16x8 kf1 = *(const bf16x8*)&Kl[(krow * 64 + 32 + lg * 8) ^ rswz];
#pragma unroll
      for (int nt = 0; nt < 4; ++nt) {
        sf[kt][nt] = mfma16(kf0, qf[nt][0], sf[kt][nt]);
        sf[kt][nt] = mfma16(kf1, qf[nt][1], sf[kt][nt]);
      }
    }

    // ---- mask + online softmax per token column, write P to LDS ----
#pragma unroll
    for (int nt = 0; nt < 4; ++nt) {
      int tok = t0 + nt * 16 + l15;
      bool bsel = true;
      if (MODE == 0) bsel = ((sel_l[nt * 16 + l15] >> j) & 1u) != 0;
      float sv[4][4];
      float pmax = -INFINITY;
#pragma unroll
      for (int kt = 0; kt < 4; ++kt) {
#pragma unroll
        for (int r = 0; r < 4; ++r) {
          int u = ku + kt * 16 + lg * 4 + r;
          bool vis = (u <= tok) && bsel;
          if (MODE == 1) vis = (u <= tok) && (u + WWIN > tok);
          float s = vis ? sf[kt][nt][r] * 0.125f : -INFINITY;
          sv[kt][r] = s;
          pmax = fmaxf(pmax, s);
        }
      }
      pmax = fmaxf(pmax, __shfl_xor(pmax, 16));
      pmax = fmaxf(pmax, __shfl_xor(pmax, 32));
      float mnew = fmaxf(mrun[nt], pmax);
      float mc = (mnew == -INFINITY) ? 0.f : mnew;
      float fac = expf(mrun[nt] - mc);  // mrun=-inf -> 0 (O is 0 anyway)
      mrun[nt] = mnew;
      float psum = 0.f;
      unsigned short pb[16];
#pragma unroll
      for (int kt = 0; kt < 4; ++kt)
#pragma unroll
        for (int r = 0; r < 4; ++r) {
          float e = expf(sv[kt][r] - mc);  // -inf -> 0
          psum += e;
          pb[kt * 4 + r] = f2bf(e);
        }
      psum += __shfl_xor(psum, 16);
      psum += __shfl_xor(psum, 32);
      lrun[nt] = lrun[nt] * fac + psum;
#pragma unroll
      for (int dt = 0; dt < 4; ++dt)
#pragma unroll
        for (int r = 0; r < 4; ++r) oacc[dt][nt][r] *= fac;
      unsigned short* pw = &Pl[w][0];
#pragma unroll
      for (int kt = 0; kt < 4; ++kt) {
        int idx = ((nt * 16 + l15) * 64 + kt * 16 + lg * 4) ^ rswz;
        unsigned int lo = (unsigned)pb[kt * 4] | ((unsigned)pb[kt * 4 + 1] << 16);
        unsigned int hi = (unsigned)pb[kt * 4 + 2] | ((unsigned)pb[kt * 4 + 3] << 16);
        *(uint2*)&pw[idx] = make_uint2(lo, hi);
      }
    }
    __syncthreads();

    // ---- O^T += mfma(Vt, P): D[m=dim][n=token] ----
#pragma unroll
    for (int kc = 0; kc < 2; ++kc) {
      bf16x8 pf[4];
#pragma unroll
      for (int nt = 0; nt < 4; ++nt)
        pf[nt] = *(const bf16x8*)&Pl[w][((nt * 16 + l15) * 64 + kc * 32 + lg * 8) ^ rswz];
#pragma unroll
      for (int dt = 0; dt < 4; ++dt) {
        bf16x8 vf = *(const bf16x8*)&Vt[((dt * 16 + l15) * 64 + kc * 32 + lg * 8) ^ rswz];
#pragma unroll
        for (int nt = 0; nt < 4; ++nt)
          oacc[dt][nt] = mfma16(vf, pf[nt], oacc[dt][nt]);
      }
    }
    __syncthreads();
  }

  // ---- epilogue: O = O^T / l ----
#pragma unroll
  for (int nt = 0; nt < 4; ++nt) {
    float inv = (lrun[nt] > 0.f) ? 1.f / lrun[nt] : 0.f;
    int tok = t0 + nt * 16 + l15;
    float* ob = O + ((size_t)tok * H + g * HPG + w) * 64;
#pragma unroll
    for (int dt = 0; dt < 4; ++dt) {
      float4 v;
      v.x = oacc[dt][nt][0] * inv;
      v.y = oacc[dt][nt][1] * inv;
      v.z = oacc[dt][nt][2] * inv;
      v.w = oacc[dt][nt][3] * inv;
      *(float4*)(ob + dt * 16 + lg * 4) = v;
    }
  }
}

// ---------------- gating MLP ---------------------------------------------------
__global__ void gate_kernel(const float* __restrict__ Q, const float* __restrict__ w1,
                            const float* __restrict__ b1, const float* __restrict__ w2,
                            const float* __restrict__ b2, float* __restrict__ gates) {
  int idx = blockIdx.x * blockDim.x + threadIdx.x;
  if (idx >= S * G) return;
  int s = idx >> 2, g = idx & 3;
  float qm[64];
#pragma unroll
  for (int d = 0; d < 64; ++d) {
    float a = 0.f;
    for (int hp = 0; hp < HPG; ++hp) a += Q[(size_t)(s * H + g * HPG + hp) * 64 + d];
    qm[d] = a * 0.25f;
  }
  float gl[3] = {b2[0], b2[1], b2[2]};
  for (int j = 0; j < GH; ++j) {
    float z = b1[j];
    for (int d = 0; d < 64; ++d) z += qm[d] * w1[d * GH + j];
    float sl = z / (1.f + expf(-z));
    gl[0] += sl * w2[j * 3 + 0];
    gl[1] += sl * w2[j * 3 + 1];
    gl[2] += sl * w2[j * 3 + 2];
  }
  float m = fmaxf(gl[0], fmaxf(gl[1], gl[2]));
  float e0 = expf(gl[0] - m), e1 = expf(gl[1] - m), e2 = expf(gl[2] - m);
  float inv = 1.f / (e0 + e1 + e2);
  float p0 = e0 * inv, p1 = e1 * inv, p2 = e2 * inv;
  int am = (gl[0] >= gl[1] && gl[0] >= gl[2]) ? 0 : ((gl[1] >= gl[2]) ? 1 : 2);
  float t1 = (am == 0) ? fmaxf(gl[1], gl[2]) : ((am == 1) ? fmaxf(gl[0], gl[2]) : fmaxf(gl[0], gl[1]));
  if (m - t1 > 50.f) {
    p0 = (am == 0) ? 1.f : 0.f;
    p1 = (am == 1) ? 1.f : 0.f;
    p2 = (am == 2) ? 1.f : 0.f;
  }
  gates[idx * 3 + 0] = p0;
  gates[idx * 3 + 1] = p1;
  gates[idx * 3 + 2] = p2;
}

// ---------------- combine branches ---------------------------------------------
__global__ void combine(const float* __restrict__ Oc, const float* __restrict__ Os,
                        const float* __restrict__ Ow, const float* __restrict__ gates,
                        float* __restrict__ O) {
  int idx = blockIdx.x * blockDim.x + threadIdx.x;
  if (idx >= S * H * DV) return;
  int h = (idx >> 6) & 15;
  int s = idx >> 10;
  int g = h >> 2;
  const float* gp = &gates[(size_t)(s * G + g) * 3];
  O[idx] = gp[0] * Oc[idx] + gp[1] * Os[idx] + gp[2] * Ow[idx];
}

// ---------------- host launch ---------------------------------------------------
extern "C" void kernel_launch(void* const* d_in, const int* in_sizes, int n_in,
                              void* d_out, int out_size, void* d_ws, size_t ws_size,
                              hipStream_t stream) {
  const float* x = (const float*)d_in[0];
  const float* W_Q = (const float*)d_in[1];
  const float* W_K_sel = (const float*)d_in[2];
  const float* W_V_sel = (const float*)d_in[3];
  const float* W_K_win = (const float*)d_in[4];
  const float* W_V_win = (const float*)d_in[5];
  const float* W_K_cmp = (const float*)d_in[6];
  const float* W_V_cmp = (const float*)d_in[7];
  const float* W_out = (const float*)d_in[8];
  const float* gw1 = (const float*)d_in[9];
  const float* gb1 = (const float*)d_in[10];
  const float* gw2 = (const float*)d_in[11];
  const float* gb2 = (const float*)d_in[12];

  float* w = (float*)d_ws;
  float* cosT = w;  w += S * 32;
  float* sinT = w;  w += S * 32;
  float* Qb   = w;  w += S * H * DK;
  float* Ksel = w;  w += S * G * DK;   // KV block: 6 consecutive S*256 buffers
  float* Vsel = w;  w += S * G * DV;
  float* Kwin = w;  w += S * G * DK;
  float* Vwin = w;  w += S * G * DV;
  float* Kcr  = w;  w += S * G * DK;
  float* Vcr  = w;  w += S * G * DV;
  float* Kc   = w;  w += G * NCMP * DK;
  float* Vc   = w;  w += G * NCMP * DV;
  float* Ocmp = w;  w += S * H * DV;
  float* Osel = w;  w += S * H * DV;
  float* Owin = w;  w += S * H * DV;
  float* gates= w;  w += S * G * 3;
  float* Ocomb= w;  w += S * H * DV;
  unsigned int* selm = (unsigned int*)w;

  rope_table<<<(S * 32 + 255) / 256, 256, 0, stream>>>(cosT, sinT);

  gemm_f32<<<dim3(DIM / 64, S / 64), 256, 0, stream>>>(x, W_Q, Qb, H * DK, DIM);
  gemm_kv<<<dim3(4, S / 64, 6), 256, 0, stream>>>(x, W_K_sel, W_V_sel, W_K_win,
                                                  W_V_win, W_K_cmp, W_V_cmp, Ksel);

  rope_apply<<<(S * H * 32 + 255) / 256, 256, 0, stream>>>(Qb, cosT, sinT, H, S * H * 32);
  rope_apply<<<(S * G * 32 + 255) / 256, 256, 0, stream>>>(Ksel, cosT, sinT, G, S * G * 32);
  rope_apply<<<(S * G * 32 + 255) / 256, 256, 0, stream>>>(Kwin, cosT, sinT, G, S * G * 32);
  rope_apply<<<(S * G * 32 + 255) / 256, 256, 0, stream>>>(Kcr, cosT, sinT, G, S * G * 32);

  pool_cmp<<<dim3(NCMP, G), 64, 0, stream>>>(Kcr, Vcr, Kc, Vc);

  cmp_attn<<<dim3(S, G), 256, 0, stream>>>(Qb, Kc, Vc, Ocmp, selm);
  attn_mfma<0><<<dim3(S / 64, G), 256, 0, stream>>>(Qb, Ksel, Vsel, selm, Osel);
  attn_mfma<1><<<dim3(S / 64, G), 256, 0, stream>>>(Qb, Kwin, Vwin, selm, Owin);

  gate_kernel<<<(S * G + 255) / 256, 256, 0, stream>>>(Qb, gw1, gb1, gw2, gb2, gates);
  combine<<<(S * H * DV + 255) / 256, 256, 0, stream>>>(Ocmp, Osel, Owin, gates, Ocomb);

  gemm_f32<<<dim3(DIM / 64, S / 64), 256, 0, stream>>>(Ocomb, W_out, (float*)d_out, DIM, H * DV);
}

// Round 6
// 558.993 us; speedup vs baseline: 4.2578x; 1.2089x over previous
//
#include <hip/hip_runtime.h>
#include <math.h>

#define S 2048
#define DIM 1024
#define H 16
#define G 4
#define HPG 4
#define DK 64
#define DV 64
#define NCMP 127
#define JBLK 32
#define NSEL 16
#define WWIN 512
#define GH 32

typedef __attribute__((ext_vector_type(8))) __bf16 bf16x8;
typedef __attribute__((ext_vector_type(4))) float f32x4;

__device__ __forceinline__ unsigned short f2bf(float f) {
  unsigned u = __float_as_uint(f);
  unsigned r = (u + 0x7FFFu + ((u >> 16) & 1u)) >> 16;
  return (unsigned short)r;
}

__device__ __forceinline__ f32x4 mfma16(bf16x8 a, bf16x8 b, f32x4 c) {
  return __builtin_amdgcn_mfma_f32_16x16x32_bf16(a, b, c, 0, 0, 0);
}

// ---------------- RoPE cos/sin table (fp64-accurate, matches np reference) ---
__global__ void rope_table(float* __restrict__ cosT, float* __restrict__ sinT) {
  int idx = blockIdx.x * blockDim.x + threadIdx.x;
  if (idx >= S * 32) return;
  int s = idx >> 5, i = idx & 31;
  double inv = pow(10000.0, -2.0 * (double)i / 64.0);
  double ang = (double)s * inv;
  cosT[idx] = (float)cos(ang);
  sinT[idx] = (float)sin(ang);
}

// ---------------- fp32 tiled GEMM body (64x64 tile, 4x4/thread) --------------
__device__ __forceinline__ void gemm_body(const float* __restrict__ A,
                                          const float* __restrict__ B,
                                          float* __restrict__ C,
                                          int N, int K, int bm, int bn,
                                          float (*As)[64], float (*Bs)[64]) {
  int tid = threadIdx.x;
  int tr = tid >> 4, tc = tid & 15;
  float acc[4][4] = {{0.f}};
  int arow = tid >> 2;
  int acol = (tid & 3) << 2;
  int brow = tid >> 4;
  int bcol = (tid & 15) << 2;
  const float* Ab = A + (size_t)(bm * 64) * K;
  const float* Bb = B + bn * 64;
  for (int k0 = 0; k0 < K; k0 += 16) {
    float4 av = *(const float4*)(Ab + (size_t)arow * K + k0 + acol);
    float4 bv = *(const float4*)(Bb + (size_t)(k0 + brow) * N + bcol);
    As[acol + 0][arow] = av.x;
    As[acol + 1][arow] = av.y;
    As[acol + 2][arow] = av.z;
    As[acol + 3][arow] = av.w;
    *(float4*)(&Bs[brow][bcol]) = bv;
    __syncthreads();
#pragma unroll
    for (int kk = 0; kk < 16; ++kk) {
      float a[4], b[4];
#pragma unroll
      for (int q = 0; q < 4; ++q) {
        a[q] = As[kk][(tr << 2) + q];
        b[q] = Bs[kk][(tc << 2) + q];
      }
#pragma unroll
      for (int i = 0; i < 4; ++i)
#pragma unroll
        for (int jj = 0; jj < 4; ++jj) acc[i][jj] += a[i] * b[jj];
    }
    __syncthreads();
  }
  for (int i = 0; i < 4; ++i)
    for (int jj = 0; jj < 4; ++jj)
      C[(size_t)(bm * 64 + (tr << 2) + i) * N + bn * 64 + (tc << 2) + jj] = acc[i][jj];
}

__global__ __launch_bounds__(256) void gemm_f32(const float* __restrict__ A,
                                                const float* __restrict__ B,
                                                float* __restrict__ C,
                                                int N, int K) {
  __shared__ float As[16][64];
  __shared__ float Bs[16][64];
  gemm_body(A, B, C, N, K, blockIdx.y, blockIdx.x, As, Bs);
}

__global__ __launch_bounds__(256) void gemm_kv(const float* __restrict__ x,
                                               const float* __restrict__ W0,
                                               const float* __restrict__ W1,
                                               const float* __restrict__ W2,
                                               const float* __restrict__ W3,
                                               const float* __restrict__ W4,
                                               const float* __restrict__ W5,
                                               float* __restrict__ out) {
  __shared__ float As[16][64];
  __shared__ float Bs[16][64];
  int z = blockIdx.z;
  const float* B;
  switch (z) {
    case 0: B = W0; break;
    case 1: B = W1; break;
    case 2: B = W2; break;
    case 3: B = W3; break;
    case 4: B = W4; break;
    default: B = W5; break;
  }
  gemm_body(x, B, out + (size_t)z * S * 256, 256, DIM, blockIdx.y, blockIdx.x, As, Bs);
}

// ---------------- in-place RoPE on [S][NH][64] (fp32, for Q and Kcr) ----------
__global__ void rope_apply(float* __restrict__ a, const float* __restrict__ cosT,
                           const float* __restrict__ sinT, int NH, int total) {
  int idx = blockIdx.x * blockDim.x + threadIdx.x;
  if (idx >= total) return;
  int i = idx & 31;
  int rest = idx >> 5;
  int n = rest % NH;
  int s = rest / NH;
  float c = cosT[s * 32 + i], sn = sinT[s * 32 + i];
  float* base = a + (size_t)(s * NH + n) * 64;
  float x1 = base[i], x2 = base[i + 32];
  base[i] = x1 * c - x2 * sn;
  base[i + 32] = x2 * c + x1 * sn;
}

// ---------------- fused RoPE + bf16 convert: [S][G][64] fp32 -> [g][S][64] bf16
__global__ __launch_bounds__(256) void rope_bf16(const float* __restrict__ Kf,
                                                 const float* __restrict__ cosT,
                                                 const float* __restrict__ sinT,
                                                 unsigned short* __restrict__ Kb) {
  int tid = threadIdx.x;
  int sl = tid >> 5, d = tid & 31;
  int s = blockIdx.x * 8 + sl;
  int g = blockIdx.y;
  float x1 = Kf[(size_t)(s * G + g) * 64 + d];
  float x2 = Kf[(size_t)(s * G + g) * 64 + d + 32];
  float c = cosT[s * 32 + d], sn = sinT[s * 32 + d];
  Kb[((size_t)g * S + s) * 64 + d] = f2bf(x1 * c - x2 * sn);
  Kb[((size_t)g * S + s) * 64 + d + 32] = f2bf(x2 * c + x1 * sn);
}

// ---------------- V transpose + bf16: [S][G][64] fp32 -> [g][64][S] bf16 ------
__global__ __launch_bounds__(256) void vtrans_bf16(const float* __restrict__ V,
                                                   unsigned short* __restrict__ Vt) {
  int tid = threadIdx.x;
  int s0 = blockIdx.x * 64;
  int g = blockIdx.y;
  int dim = tid >> 2, c0 = (tid & 3) * 16;
  union { unsigned short us[16]; float4 f4[2]; } t;
#pragma unroll
  for (int i = 0; i < 16; ++i)
    t.us[i] = f2bf(V[(size_t)((s0 + c0 + i) * G + g) * 64 + dim]);
  unsigned short* o = Vt + ((size_t)g * 64 + dim) * S + s0 + c0;
  *(float4*)o = t.f4[0];
  *(float4*)(o + 8) = t.f4[1];
}

// ---------------- Q fp32 -> bf16 (same [s][h][64] layout) ---------------------
__global__ __launch_bounds__(256) void qconv(const float* __restrict__ Qf,
                                             unsigned short* __restrict__ Qb) {
  int idx = (blockIdx.x * 256 + threadIdx.x) * 8;
  float4 a = *(const float4*)&Qf[idx];
  float4 b = *(const float4*)&Qf[idx + 4];
  union { unsigned short us[8]; float4 f4; } t;
  t.us[0] = f2bf(a.x); t.us[1] = f2bf(a.y); t.us[2] = f2bf(a.z); t.us[3] = f2bf(a.w);
  t.us[4] = f2bf(b.x); t.us[5] = f2bf(b.y); t.us[6] = f2bf(b.z); t.us[7] = f2bf(b.w);
  *(float4*)&Qb[idx] = t.f4;
}

// ---------------- avg-pool compressed K/V -------------------------------------
__global__ void pool_cmp(const float* __restrict__ Kcr, const float* __restrict__ Vcr,
                         float* __restrict__ Kc, float* __restrict__ Vc) {
  int c = blockIdx.x, g = blockIdx.y, d = threadIdx.x;
  float sk = 0.f, sv = 0.f;
  for (int l = 0; l < 32; ++l) {
    int t = c * 16 + l;
    sk += Kcr[(size_t)(t * G + g) * 64 + d];
    sv += Vcr[(size_t)(t * G + g) * 64 + d];
  }
  Kc[(size_t)(g * NCMP + c) * 64 + d] = sk * (1.f / 32.f);
  Vc[(size_t)(g * NCMP + c) * 64 + d] = sv * (1.f / 32.f);
}

// ---------------- compressed attention + selection top-k (fp32, exact) --------
__global__ __launch_bounds__(256) void cmp_attn(const float* __restrict__ Q,
                                                const float* __restrict__ Kc,
                                                const float* __restrict__ Vc,
                                                float* __restrict__ Ocmp,
                                                unsigned int* __restrict__ selm) {
  int s = blockIdx.x, g = blockIdx.y;
  __shared__ float q4[4][64];
  __shared__ float sc[4][128];
  __shared__ float pgp[4][JBLK];
  __shared__ float pg[JBLK];
  int tid = threadIdx.x;
  {
    int h = tid >> 6, d = tid & 63;
    q4[h][d] = Q[(size_t)(s * H + g * HPG + h) * 64 + d];
  }
  __syncthreads();

  if (tid < NCMP) {
    int c = tid;
    bool vis = (c * 16 + 32 <= s + 1);
    float a0 = 0.f, a1 = 0.f, a2 = 0.f, a3 = 0.f;
    const float* kr = &Kc[(size_t)(g * NCMP + c) * 64];
#pragma unroll 4
    for (int kk = 0; kk < 16; ++kk) {
      float4 kv = *(const float4*)&kr[kk * 4];
      float4 q0 = *(const float4*)&q4[0][kk * 4];
      float4 q1 = *(const float4*)&q4[1][kk * 4];
      float4 q2 = *(const float4*)&q4[2][kk * 4];
      float4 q3 = *(const float4*)&q4[3][kk * 4];
      a0 += q0.x * kv.x + q0.y * kv.y + q0.z * kv.z + q0.w * kv.w;
      a1 += q1.x * kv.x + q1.y * kv.y + q1.z * kv.z + q1.w * kv.w;
      a2 += q2.x * kv.x + q2.y * kv.y + q2.z * kv.z + q2.w * kv.w;
      a3 += q3.x * kv.x + q3.y * kv.y + q3.z * kv.z + q3.w * kv.w;
    }
    sc[0][c] = vis ? a0 * 0.125f : -INFINITY;
    sc[1][c] = vis ? a1 * 0.125f : -INFINITY;
    sc[2][c] = vis ? a2 * 0.125f : -INFINITY;
    sc[3][c] = vis ? a3 * 0.125f : -INFINITY;
  }
  __syncthreads();

  int w = tid >> 6, lane = tid & 63;
  {
    float v0 = sc[w][lane];
    float v1 = (lane + 64 < NCMP) ? sc[w][lane + 64] : -INFINITY;
    float m = fmaxf(v0, v1);
    for (int off = 32; off; off >>= 1) m = fmaxf(m, __shfl_xor(m, off));
    float e0 = (m > -INFINITY && v0 > -INFINITY) ? expf(v0 - m) : 0.f;
    float e1 = (m > -INFINITY && v1 > -INFINITY) ? expf(v1 - m) : 0.f;
    float sum = e0 + e1;
    for (int off = 32; off; off >>= 1) sum += __shfl_xor(sum, off);
    float inv = (sum > 0.f) ? 1.f / sum : 0.f;
    sc[w][lane] = e0 * inv;
    if (lane + 64 < NCMP) sc[w][lane + 64] = e1 * inv;
  }
  __syncthreads();

  {
    int h = tid >> 6, d = tid & 63;
    float o = 0.f;
#pragma unroll 4
    for (int c = 0; c < NCMP; ++c) o += sc[h][c] * Vc[(size_t)(g * NCMP + c) * 64 + d];
    Ocmp[(size_t)(s * H + g * HPG + h) * 64 + d] = o;
  }

  if (tid < 128) {
    int h = tid >> 5, j = tid & 31;
    float a = 0.f;
    for (int c = 0; c < NCMP; ++c) {
      int lo = max(c * 16, j * 64);
      int hi = min(c * 16 + 32, j * 64 + 64);
      if (hi > lo) a += sc[h][c] * (float)(hi - lo) * (1.f / 32.f);
    }
    pgp[h][j] = a;
  }
  __syncthreads();
  if (tid < JBLK) pg[tid] = pgp[0][tid] + pgp[1][tid] + pgp[2][tid] + pgp[3][tid];
  __syncthreads();

  if (tid == 0) {
    float scj[JBLK];
    int cur = s >> 6;
    for (int j = 0; j < JBLK; ++j) {
      float v = (j * 64 <= s) ? pg[j] : -1e30f;
      if (j == 0 || j == cur) v = 1e9f;
      scj[j] = v;
    }
    unsigned int mask = 0;
    for (int n = 0; n < NSEL; ++n) {
      int bi = 0;
      float bv = -INFINITY;
      for (int j = 0; j < JBLK; ++j)
        if (scj[j] > bv) { bv = scj[j]; bi = j; }
      mask |= 1u << bi;
      scj[bi] = -INFINITY;
    }
    selm[s * G + g] = mask;
  }
}

// ---------------- fused MFMA flash attention: sel (z=0) / win (z=1) -----------
// block = (32-token tile, group, mode); 4 waves = 4 heads.
__global__ __launch_bounds__(256) void attn_fused(
    const unsigned short* __restrict__ Qbf,
    const unsigned short* __restrict__ Kbs, const unsigned short* __restrict__ Vts,
    const unsigned short* __restrict__ Kbw, const unsigned short* __restrict__ Vtw,
    const unsigned int* __restrict__ selm,
    float* __restrict__ Osel, float* __restrict__ Owin) {
  __shared__ unsigned short Kl[64 * 64];     // [key][dim], swizzled
  __shared__ unsigned short Vt[64 * 64];     // [dim][key], swizzled
  __shared__ unsigned short Pl[4][32 * 64];  // per wave: [token][key], swizzled
  __shared__ unsigned int sel_l[32];
  __shared__ int blist[JBLK];
  __shared__ int nB_s;

  int t0 = blockIdx.x * 32;
  int g = blockIdx.y;
  int mode = blockIdx.z;
  int tid = threadIdx.x;
  int w = tid >> 6, lane = tid & 63;
  int l15 = lane & 15, lg = lane >> 4;
  int rswz = (l15 & 7) << 3;

  const unsigned short* Kb = mode ? Kbw : Kbs;
  const unsigned short* Vtb = mode ? Vtw : Vts;
  float* O = mode ? Owin : Osel;

  if (mode == 0 && tid < 32) sel_l[tid] = selm[(t0 + tid) * G + g];
  __syncthreads();
  if (tid == 0) {
    int n = 0;
    if (mode == 0) {
      unsigned int un = 0;
      for (int i = 0; i < 32; ++i) un |= sel_l[i];
      for (int j = 0; j < JBLK; ++j)
        if ((un >> j) & 1u) blist[n++] = j;
    } else {
      int jt = (t0 + 31) >> 6;
      int lo = t0 - (WWIN - 1);  // oldest key visible to the FIRST token of tile
      int j0 = (lo > 0) ? (lo >> 6) : 0;
      for (int j = j0; j <= jt; ++j) blist[n++] = j;
    }
    nB_s = n;
  }
  __syncthreads();
  int nB = nB_s;

  // Q fragments (B operand): token = t0 + nt*16 + l15, dims kc*32 + lg*8
  bf16x8 qf[2][2];
#pragma unroll
  for (int nt = 0; nt < 2; ++nt) {
    const unsigned short* qb =
        Qbf + ((size_t)(t0 + nt * 16 + l15) * H + g * HPG + w) * 64;
#pragma unroll
    for (int kc = 0; kc < 2; ++kc)
      qf[nt][kc] = *(const bf16x8*)(qb + kc * 32 + lg * 8);
  }

  float mrun[2], lrun[2];
  f32x4 oacc[4][2];  // [dt][nt]
#pragma unroll
  for (int nt = 0; nt < 2; ++nt) {
    mrun[nt] = -INFINITY;
    lrun[nt] = 0.f;
#pragma unroll
    for (int dt = 0; dt < 4; ++dt) oacc[dt][nt] = (f32x4){0.f, 0.f, 0.f, 0.f};
  }

  for (int b = 0; b < nB; ++b) {
    int j = blist[b];
    int ku = j * 64;

    // ---- stage K (coalesced 16B, swizzled chunk) ----
    {
      const unsigned short* src = Kb + ((size_t)g * S + ku) * 64;
#pragma unroll
      for (int c2 = 0; c2 < 2; ++c2) {
        int chunk = tid + c2 * 256;
        int key = chunk >> 3, cc = chunk & 7;
        *(float4*)&Kl[key * 64 + ((cc ^ (key & 7)) << 3)] =
            *(const float4*)(src + chunk * 8);
      }
    }
    // ---- stage Vt (coalesced 16B rows, swizzled chunk) ----
    {
#pragma unroll
      for (int c2 = 0; c2 < 2; ++c2) {
        int chunk = tid + c2 * 256;
        int dim = chunk >> 3, cc = chunk & 7;
        *(float4*)&Vt[dim * 64 + ((cc ^ (dim & 7)) << 3)] =
            *(const float4*)(Vtb + ((size_t)g * 64 + dim) * S + ku + cc * 8);
      }
    }
    __syncthreads();

    // ---- S^T = mfma(K, Q): D[m=key][n=token] ----
    f32x4 sf[4][2];
#pragma unroll
    for (int kt = 0; kt < 4; ++kt)
#pragma unroll
      for (int nt = 0; nt < 2; ++nt) sf[kt][nt] = (f32x4){0.f, 0.f, 0.f, 0.f};
#pragma unroll
    for (int kt = 0; kt < 4; ++kt) {
      int krow = kt * 16 + l15;
      bf16x8 kf0 = *(const bf16x8*)&Kl[(krow * 64 + lg * 8) ^ rswz];
      bf16x8 kf1 = *(const bf16x8*)&Kl[(krow * 64 + 32 + lg * 8) ^ rswz];
#pragma unroll
      for (int nt = 0; nt < 2; ++nt) {
        sf[kt][nt] = mfma16(kf0, qf[nt][0], sf[kt][nt]);
        sf[kt][nt] = mfma16(kf1, qf[nt][1], sf[kt][nt]);
      }
    }

    // ---- mask + online softmax per token column, write P to LDS ----
#pragma unroll
    for (int nt = 0; nt < 2; ++nt) {
      int tok = t0 + nt * 16 + l15;
      bool bsel = true;
      if (mode == 0) bsel = ((sel_l[nt * 16 + l15] >> j) & 1u) != 0;
      float sv[4][4];
      float pmax = -INFINITY;
#pragma unroll
      for (int kt = 0; kt < 4; ++kt) {
#pragma unroll
        for (int r = 0; r < 4; ++r) {
          int u = ku + kt * 16 + lg * 4 + r;
          bool vis = mode ? ((u <= tok) && (u + WWIN > tok)) : ((u <= tok) && bsel);
          float s = vis ? sf[kt][nt][r] * 0.125f : -INFINITY;
          sv[kt][r] = s;
          pmax = fmaxf(pmax, s);
        }
      }
      pmax = fmaxf(pmax, __shfl_xor(pmax, 16));
      pmax = fmaxf(pmax, __shfl_xor(pmax, 32));
      float mnew = fmaxf(mrun[nt], pmax);
      float mc = (mnew == -INFINITY) ? 0.f : mnew;
      float fac = expf(mrun[nt] - mc);
      mrun[nt] = mnew;
      float psum = 0.f;
      unsigned short pb[16];
#pragma unroll
      for (int kt = 0; kt < 4; ++kt)
#pragma unroll
        for (int r = 0; r < 4; ++r) {
          float e = expf(sv[kt][r] - mc);
          psum += e;
          pb[kt * 4 + r] = f2bf(e);
        }
      psum += __shfl_xor(psum, 16);
      psum += __shfl_xor(psum, 32);
      lrun[nt] = lrun[nt] * fac + psum;
#pragma unroll
      for (int dt = 0; dt < 4; ++dt)
#pragma unroll
        for (int r = 0; r < 4; ++r) oacc[dt][nt][r] *= fac;
      unsigned short* pw = &Pl[w][0];
#pragma unroll
      for (int kt = 0; kt < 4; ++kt) {
        int idx = ((nt * 16 + l15) * 64 + kt * 16 + lg * 4) ^ rswz;
        unsigned int lo = (unsigned)pb[kt * 4] | ((unsigned)pb[kt * 4 + 1] << 16);
        unsigned int hi = (unsigned)pb[kt * 4 + 2] | ((unsigned)pb[kt * 4 + 3] << 16);
        *(uint2*)&pw[idx] = make_uint2(lo, hi);
      }
    }

    // ---- O^T += mfma(Vt, P): D[m=dim][n=token] (Pl is per-wave, no barrier) --
#pragma unroll
    for (int kc = 0; kc < 2; ++kc) {
      bf16x8 pf[2];
#pragma unroll
      for (int nt = 0; nt < 2; ++nt)
        pf[nt] = *(const bf16x8*)&Pl[w][((nt * 16 + l15) * 64 + kc * 32 + lg * 8) ^ rswz];
#pragma unroll
      for (int dt = 0; dt < 4; ++dt) {
        bf16x8 vf = *(const bf16x8*)&Vt[((dt * 16 + l15) * 64 + kc * 32 + lg * 8) ^ rswz];
#pragma unroll
        for (int nt = 0; nt < 2; ++nt)
          oacc[dt][nt] = mfma16(vf, pf[nt], oacc[dt][nt]);
      }
    }
    __syncthreads();
  }

  // ---- epilogue: O = O^T / l ----
#pragma unroll
  for (int nt = 0; nt < 2; ++nt) {
    float inv = (lrun[nt] > 0.f) ? 1.f / lrun[nt] : 0.f;
    int tok = t0 + nt * 16 + l15;
    float* ob = O + ((size_t)tok * H + g * HPG + w) * 64;
#pragma unroll
    for (int dt = 0; dt < 4; ++dt) {
      float4 v;
      v.x = oacc[dt][nt][0] * inv;
      v.y = oacc[dt][nt][1] * inv;
      v.z = oacc[dt][nt][2] * inv;
      v.w = oacc[dt][nt][3] * inv;
      *(float4*)(ob + dt * 16 + lg * 4) = v;
    }
  }
}

// ---------------- gating MLP ---------------------------------------------------
__global__ void gate_kernel(const float* __restrict__ Q, const float* __restrict__ w1,
                            const float* __restrict__ b1, const float* __restrict__ w2,
                            const float* __restrict__ b2, float* __restrict__ gates) {
  int idx = blockIdx.x * blockDim.x + threadIdx.x;
  if (idx >= S * G) return;
  int s = idx >> 2, g = idx & 3;
  float qm[64];
#pragma unroll
  for (int d = 0; d < 64; ++d) {
    float a = 0.f;
    for (int hp = 0; hp < HPG; ++hp) a += Q[(size_t)(s * H + g * HPG + hp) * 64 + d];
    qm[d] = a * 0.25f;
  }
  float gl[3] = {b2[0], b2[1], b2[2]};
  for (int j = 0; j < GH; ++j) {
    float z = b1[j];
    for (int d = 0; d < 64; ++d) z += qm[d] * w1[d * GH + j];
    float sl = z / (1.f + expf(-z));
    gl[0] += sl * w2[j * 3 + 0];
    gl[1] += sl * w2[j * 3 + 1];
    gl[2] += sl * w2[j * 3 + 2];
  }
  float m = fmaxf(gl[0], fmaxf(gl[1], gl[2]));
  float e0 = expf(gl[0] - m), e1 = expf(gl[1] - m), e2 = expf(gl[2] - m);
  float inv = 1.f / (e0 + e1 + e2);
  float p0 = e0 * inv, p1 = e1 * inv, p2 = e2 * inv;
  int am = (gl[0] >= gl[1] && gl[0] >= gl[2]) ? 0 : ((gl[1] >= gl[2]) ? 1 : 2);
  float t1 = (am == 0) ? fmaxf(gl[1], gl[2]) : ((am == 1) ? fmaxf(gl[0], gl[2]) : fmaxf(gl[0], gl[1]));
  if (m - t1 > 50.f) {
    p0 = (am == 0) ? 1.f : 0.f;
    p1 = (am == 1) ? 1.f : 0.f;
    p2 = (am == 2) ? 1.f : 0.f;
  }
  gates[idx * 3 + 0] = p0;
  gates[idx * 3 + 1] = p1;
  gates[idx * 3 + 2] = p2;
}

// ---------------- combine branches (in place into Oc) --------------------------
__global__ void combine(float* __restrict__ Oc, const float* __restrict__ Os,
                        const float* __restrict__ Ow, const float* __restrict__ gates) {
  int idx = blockIdx.x * blockDim.x + threadIdx.x;
  if (idx >= S * H * DV) return;
  int h = (idx >> 6) & 15;
  int s = idx >> 10;
  int g = h >> 2;
  const float* gp = &gates[(size_t)(s * G + g) * 3];
  Oc[idx] = gp[0] * Oc[idx] + gp[1] * Os[idx] + gp[2] * Ow[idx];
}

// ---------------- host launch ---------------------------------------------------
extern "C" void kernel_launch(void* const* d_in, const int* in_sizes, int n_in,
                              void* d_out, int out_size, void* d_ws, size_t ws_size,
                              hipStream_t stream) {
  const float* x = (const float*)d_in[0];
  const float* W_Q = (const float*)d_in[1];
  const float* W_K_sel = (const float*)d_in[2];
  const float* W_V_sel = (const float*)d_in[3];
  const float* W_K_win = (const float*)d_in[4];
  const float* W_V_win = (const float*)d_in[5];
  const float* W_K_cmp = (const float*)d_in[6];
  const float* W_V_cmp = (const float*)d_in[7];
  const float* W_out = (const float*)d_in[8];
  const float* gw1 = (const float*)d_in[9];
  const float* gb1 = (const float*)d_in[10];
  const float* gw2 = (const float*)d_in[11];
  const float* gb2 = (const float*)d_in[12];

  float* w = (float*)d_ws;
  float* cosT = w;  w += S * 32;
  float* sinT = w;  w += S * 32;
  float* Qb   = w;  w += S * H * DK;
  float* Ksel = w;  w += S * G * DK;   // KV block: 6 consecutive S*256 buffers
  float* Vsel = w;  w += S * G * DV;
  float* Kwin = w;  w += S * G * DK;
  float* Vwin = w;  w += S * G * DV;
  float* Kcr  = w;  w += S * G * DK;
  float* Vcr  = w;  w += S * G * DV;
  float* Kc   = w;  w += G * NCMP * DK;
  float* Vc   = w;  w += G * NCMP * DV;
  float* Ocmp = w;  w += S * H * DV;
  float* Osel = w;  w += S * H * DV;
  float* Owin = w;  w += S * H * DV;
  float* gates= w;  w += S * G * 3;
  unsigned int* selm = (unsigned int*)w;  w += S * G;
  unsigned short* Kbf_s = (unsigned short*)w;  w += (size_t)G * S * 64 / 2;
  unsigned short* Kbf_w = (unsigned short*)w;  w += (size_t)G * S * 64 / 2;
  unsigned short* Vt_s  = (unsigned short*)w;  w += (size_t)G * S * 64 / 2;
  unsigned short* Vt_w  = (unsigned short*)w;  w += (size_t)G * S * 64 / 2;
  unsigned short* Qbf   = (unsigned short*)w;  w += (size_t)S * H * 64 / 2;

  rope_table<<<(S * 32 + 255) / 256, 256, 0, stream>>>(cosT, sinT);

  gemm_f32<<<dim3(DIM / 64, S / 64), 256, 0, stream>>>(x, W_Q, Qb, H * DK, DIM);
  gemm_kv<<<dim3(4, S / 64, 6), 256, 0, stream>>>(x, W_K_sel, W_V_sel, W_K_win,
                                                  W_V_win, W_K_cmp, W_V_cmp, Ksel);

  rope_apply<<<(S * H * 32 + 255) / 256, 256, 0, stream>>>(Qb, cosT, sinT, H, S * H * 32);
  rope_apply<<<(S * G * 32 + 255) / 256, 256, 0, stream>>>(Kcr, cosT, sinT, G, S * G * 32);

  rope_bf16<<<dim3(S / 8, G), 256, 0, stream>>>(Ksel, cosT, sinT, Kbf_s);
  rope_bf16<<<dim3(S / 8, G), 256, 0, stream>>>(Kwin, cosT, sinT, Kbf_w);
  vtrans_bf16<<<dim3(S / 64, G), 256, 0, stream>>>(Vsel, Vt_s);
  vtrans_bf16<<<dim3(S / 64, G), 256, 0, stream>>>(Vwin, Vt_w);
  qconv<<<(S * H * 64) / (256 * 8), 256, 0, stream>>>(Qb, Qbf);

  pool_cmp<<<dim3(NCMP, G), 64, 0, stream>>>(Kcr, Vcr, Kc, Vc);

  cmp_attn<<<dim3(S, G), 256, 0, stream>>>(Qb, Kc, Vc, Ocmp, selm);
  attn_fused<<<dim3(S / 32, G, 2), 256, 0, stream>>>(Qbf, Kbf_s, Vt_s, Kbf_w, Vt_w,
                                                     selm, Osel, Owin);

  gate_kernel<<<(S * G + 255) / 256, 256, 0, stream>>>(Qb, gw1, gb1, gw2, gb2, gates);
  combine<<<(S * H * DV + 255) / 256, 256, 0, stream>>>(Ocmp, Osel, Owin, gates);

  gemm_f32<<<dim3(DIM / 64, S / 64), 256, 0, stream>>>(Ocmp, W_out, (float*)d_out, DIM, H * DV);
}